// Round 4
// baseline (698.211 us; speedup 1.0000x reference)
//
#include <hip/hip_runtime.h>
#include <stdint.h>
#include <math.h>

#define NS 8
#define K3B 512
#define NBINS 8192
#define CANDC 2048
#define CAND_MIN 128
#define NEGV -1e30f
#define EPSV 1e-5f

__device__ __forceinline__ uint32_t toOrd(float f) {
  uint32_t u = __float_as_uint(f);
  return (u & 0x80000000u) ? ~u : (u | 0x80000000u);
}
__device__ __forceinline__ float fromOrd(uint32_t o) {
  uint32_t u = (o & 0x80000000u) ? (o & 0x7fffffffu) : ~o;
  return __uint_as_float(u);
}

// ---- K3': one-pass fused: reg-cached chunk -> max+hist -> bstar -> S/Sx/collect ----
__global__ void __launch_bounds__(K3B, 4)
k3_fused(const float* __restrict__ logits, const float* __restrict__ temp_,
         float* __restrict__ pmax, float* __restrict__ pS, float* __restrict__ pSx,
         uint32_t* __restrict__ ccnt, uint64_t* __restrict__ cand, int V)
{
  const int chunk = blockIdx.x, row = blockIdx.y;
  const int tid = threadIdx.x, lane = tid & 63, wv = tid >> 6;
  __shared__ uint32_t h[NBINS];
  __shared__ uint32_t sfx[K3B + 1];
  __shared__ float redf[8], redf2[8];
  __shared__ int s_gsel, s_bstar;
  __shared__ float s_m;

  for (int i = tid; i < NBINS; i += K3B) h[i] = 0u;
  __syncthreads();

  const int clen = ((V + NS - 1) / NS + 3) & ~3;
  const int start = chunk * clen;
  int valid = V - start;
  if (valid < 0) valid = 0;
  if (valid > clen) valid = clen;
  const int nf4 = valid >> 2;
  const float4* p4 = (const float4*)(logits + (size_t)row * V + start);

  // load 8 float4 per thread into registers (-inf pad: bin 0, exp->0, max-neutral)
  float4 va[8];
  #pragma unroll
  for (int i = 0; i < 8; i++) {
    int f = tid + i * K3B;
    va[i] = (f < nf4) ? p4[f] : make_float4(-INFINITY, -INFINITY, -INFINITY, -INFINITY);
  }

  // pass A: max + LDS histogram
  float lmax = -INFINITY;
  #pragma unroll
  for (int i = 0; i < 8; i++) {
    float a0 = va[i].x, a1 = va[i].y, a2 = va[i].z, a3 = va[i].w;
    lmax = fmaxf(fmaxf(fmaxf(lmax, a0), fmaxf(a1, a2)), a3);
    atomicAdd(&h[toOrd(a0) >> 19], 1u);
    atomicAdd(&h[toOrd(a1) >> 19], 1u);
    atomicAdd(&h[toOrd(a2) >> 19], 1u);
    atomicAdd(&h[toOrd(a3) >> 19], 1u);
  }
  #pragma unroll
  for (int o = 32; o; o >>= 1) lmax = fmaxf(lmax, __shfl_down(lmax, o));
  if (lane == 0) redf[wv] = lmax;
  __syncthreads();

  // suffix scan over 512 groups of 16 bins
  {
    uint32_t g = 0;
    #pragma unroll
    for (int b = 0; b < 16; b++) g += h[tid * 16 + b];
    sfx[tid] = g;
    if (tid == 0) { sfx[K3B] = 0; s_gsel = 0; }
    __syncthreads();
    for (int off = 1; off < K3B; off <<= 1) {
      uint32_t v = (tid + off < K3B) ? sfx[tid + off] : 0u;
      __syncthreads();
      sfx[tid] += v;
      __syncthreads();
    }
    uint32_t gs = sfx[tid], gn = sfx[tid + 1];
    if (gs >= CAND_MIN && gn < CAND_MIN) s_gsel = tid;
    __syncthreads();
  }
  if (tid == 0) {
    int gsl = s_gsel;
    uint32_t cum = sfx[gsl + 1];
    int bsel = gsl * 16;
    for (int b = gsl * 16 + 15; b >= gsl * 16; b--) {
      cum += h[b];
      if (cum >= CAND_MIN) { bsel = b; break; }
    }
    s_bstar = bsel;
    float mm = redf[0];
    for (int w = 1; w < 8; w++) mm = fmaxf(mm, redf[w]);
    s_m = mm;
    pmax[row * NS + chunk] = mm;
  }
  __syncthreads();

  const float m_c = s_m;
  const int bst = s_bstar;
  const float t = temp_[row];
  const float safe_t = (t < EPSV) ? 1.0f : t;
  const float m_xc = m_c / safe_t;

  // pass B from registers: local-max-relative sums + candidate collect
  float S = 0.f, Sx = 0.f;
  #pragma unroll
  for (int i = 0; i < 8; i++) {
    float a[4] = {va[i].x, va[i].y, va[i].z, va[i].w};
    #pragma unroll
    for (int c = 0; c < 4; c++) {
      S += expf(a[c] - m_c);
      float x = a[c] / safe_t;
      Sx += expf(x - m_xc);
      uint32_t o = toOrd(a[c]);
      if ((int)(o >> 19) >= bst) {
        uint32_t slot = atomicAdd(&ccnt[row], 1u);
        if (slot < CANDC)
          cand[(size_t)row * CANDC + slot] =
              ((uint64_t)(~o) << 32) | (uint32_t)(start + (tid + i * K3B) * 4 + c);
      }
    }
  }
  #pragma unroll
  for (int o = 32; o; o >>= 1) { S += __shfl_down(S, o); Sx += __shfl_down(Sx, o); }
  if (lane == 0) { redf[wv] = S; redf2[wv] = Sx; }
  __syncthreads();
  if (tid == 0) {
    float s = 0, sx = 0;
    for (int w = 0; w < 8; w++) { s += redf[w]; sx += redf2[w]; }
    pS[row * NS + chunk] = s;
    pSx[row * NS + chunk] = sx;
  }
}

// ---- K4: combine partials (rescale), sort, cutoffs, gumbel argmax, rank, outputs ----
__global__ void __launch_bounds__(1024)
k4_final(const float* __restrict__ temp_, const float* __restrict__ minp_,
         const float* __restrict__ topp_, const int* __restrict__ topk_,
         const float* __restrict__ noise_,
         const float* __restrict__ pmax, const float* __restrict__ pS,
         const float* __restrict__ pSx, const uint32_t* __restrict__ ccnt,
         const uint64_t* __restrict__ candG, float* __restrict__ out,
         int B, int V, int nlp)
{
  const int row = blockIdx.x, tid = threadIdx.x, lane = tid & 63, wv = tid >> 6;
  __shared__ uint64_t cd[CANDC];
  __shared__ float redv[16], redl[16];
  __shared__ int redi[16], redr[16];
  __shared__ float sh_kth, sh_cut, sh_mpthr, sh_m, sh_L, sh_safe_t, sh_mx, sh_Sx, sh_tlp;
  __shared__ int sh_count;
  int count = (int)ccnt[row]; if (count > CANDC) count = CANDC;
  for (int e = tid; e < CANDC; e += 1024)
    cd[e] = (e < count) ? candG[(size_t)row * CANDC + e] : ~0ull;
  if (tid == 0) sh_count = count;
  __syncthreads();
  // bitonic sort ascending on key (~ord<<32 | idx) => value desc, idx asc
  for (int ks = 2; ks <= CANDC; ks <<= 1) {
    for (int j = ks >> 1; j; j >>= 1) {
      for (int e = tid; e < CANDC; e += 1024) {
        int p = e ^ j;
        if (p > e) {
          uint64_t a = cd[e], b = cd[p];
          bool up = ((e & ks) == 0);
          if ((a > b) == up) { cd[e] = b; cd[p] = a; }
        }
      }
      __syncthreads();
    }
  }
  if (tid == 0) {
    float t = temp_[row];
    float safe_t = (t < EPSV) ? 1.0f : t;
    float m = pmax[row * NS + 0];
    for (int c = 1; c < NS; c++) m = fmaxf(m, pmax[row * NS + c]);
    float m_x = m / safe_t;
    float S = 0, Sx = 0;
    for (int c = 0; c < NS; c++) {
      float mc = pmax[row * NS + c];
      S  += pS[row * NS + c]  * expf(mc - m);
      Sx += pSx[row * NS + c] * expf(mc / safe_t - m_x);
    }
    float L = logf(S);
    int i64mode = (B > 1 && topk_[1] == 0) ? 1 : 0;
    int kraw = i64mode ? topk_[2 * row] : topk_[row];
    int k = kraw < 1 ? 1 : (kraw > V ? V : kraw);
    int keff = k < count ? k : count;
    float mpthr = minp_[row] * (1.0f / Sx);
    float topp = topp_[row];
    int np = 0;
    while (np < keff) {
      float xl = fromOrd(~(uint32_t)(cd[np] >> 32)) / safe_t;
      float p = expf(xl - m_x) / Sx;
      if (p < mpthr) break;
      np++;
    }
    float kth_x = NEGV;
    if (np == k) kth_x = fromOrd(~(uint32_t)(cd[k - 1] >> 32)) / safe_t;
    int kk = np;
    float S2 = 0.f;
    for (int i = 0; i < kk; i++)
      S2 += expf(fromOrd(~(uint32_t)(cd[i] >> 32)) / safe_t - m_x);
    float cum = 0.f; int nkeep = 0;
    for (int i = 0; i < kk; i++) {
      float xl = fromOrd(~(uint32_t)(cd[i] >> 32)) / safe_t;
      float sp = expf(xl - m_x) / S2;
      cum += sp;
      if (cum - sp < topp) nkeep++;
    }
    float cutoff_x = NEGV;
    if (!(cum < topp)) {
      if (nkeep < 1) nkeep = 1;
      cutoff_x = fromOrd(~(uint32_t)(cd[nkeep - 1] >> 32)) / safe_t;
    }
    sh_kth = kth_x; sh_cut = cutoff_x; sh_mpthr = mpthr; sh_m = m; sh_L = L;
    sh_safe_t = safe_t; sh_mx = m_x; sh_Sx = Sx;
  }
  __syncthreads();
  // gumbel argmax over kept candidates (scattered noise reads)
  const int cnt_ = sh_count;
  float bestv = -INFINITY, bestl = 0.f; int besti = 0x7fffffff;
  for (int e = tid; e < cnt_; e += 1024) {
    uint64_t c = cd[e];
    float l = fromOrd(~(uint32_t)(c >> 32));
    int idx = (int)(uint32_t)(c & 0xffffffffu);
    float x = l / sh_safe_t;
    float p = expf(x - sh_mx) / sh_Sx;
    if (p >= sh_mpthr && x >= sh_kth && x >= sh_cut) {
      float u = noise_[(size_t)row * V + idx];
      float v = x + (-logf(-logf(u)));
      if (v > bestv || (v == bestv && idx < besti)) { bestv = v; besti = idx; bestl = l; }
    }
  }
  #pragma unroll
  for (int o = 32; o; o >>= 1) {
    float ov = __shfl_down(bestv, o); int oi = __shfl_down(besti, o); float ol = __shfl_down(bestl, o);
    if (ov > bestv || (ov == bestv && oi < besti)) { bestv = ov; besti = oi; bestl = ol; }
  }
  if (lane == 0) { redv[wv] = bestv; redi[wv] = besti; redl[wv] = bestl; }
  __syncthreads();
  if (tid == 0) {
    float bv = redv[0]; int bi = redi[0]; float bl = redl[0];
    for (int w = 1; w < 16; w++) {
      if (redv[w] > bv || (redv[w] == bv && redi[w] < bi)) { bv = redv[w]; bi = redi[w]; bl = redl[w]; }
    }
    float t = temp_[row];
    int sampled; float ls;
    if (t < EPSV) {
      uint64_t c0 = cd[0];
      sampled = (int)(uint32_t)(c0 & 0xffffffffu);
      ls = fromOrd(~(uint32_t)(c0 >> 32));
    } else { sampled = bi; ls = bl; }
    float token_lp = (ls - sh_m) - sh_L;
    sh_tlp = token_lp;
    float* out_idx = out + B;
    float* out_lp = out + B + (size_t)B * (1 + nlp);
    size_t rb = (size_t)row * (1 + nlp);
    out[row] = (float)sampled;
    out_idx[rb] = (float)sampled;
    out_lp[rb] = token_lp;
    for (int j = 0; j < nlp; j++) {
      uint64_t c = cd[j];
      out_idx[rb + 1 + j] = (float)(int)(uint32_t)(c & 0xffffffffu);
      out_lp[rb + 1 + j] = (fromOrd(~(uint32_t)(c >> 32)) - sh_m) - sh_L;
    }
  }
  __syncthreads();
  // rank over candidates (any element >= sampled's logit is provably a candidate)
  int rc = 0;
  for (int e = tid; e < cnt_; e += 1024) {
    float l = fromOrd(~(uint32_t)(cd[e] >> 32));
    float f = (l - sh_m) - sh_L;
    rc += (f >= sh_tlp) ? 1 : 0;
  }
  #pragma unroll
  for (int o = 32; o; o >>= 1) rc += __shfl_down(rc, o);
  if (lane == 0) redr[wv] = rc;
  __syncthreads();
  if (tid == 0) {
    int r = 0;
    for (int w = 0; w < 16; w++) r += redr[w];
    out[B + 2 * (size_t)B * (1 + nlp) + row] = (float)r;
  }
}

// ================= fallback: proven monolithic kernel (R2, passed) =================
#define FB_BLOCK 1024
#define FB_CAP 2048
#define FB_NW 16

struct FBSM {
  uint32_t hist[NBINS];
  uint64_t cand[FB_CAP];
  float redf[FB_NW];
  int   redi[FB_NW];
  int cnt; int bstar;
  float m, S, Sx;
  float kth_x, cutoff_x, mpthr;
  float L, token_lp;
  int greedy;
};

__device__ __forceinline__ float fbCandVal(const uint64_t* cand, int i) {
  return fromOrd(~(uint32_t)(cand[i] >> 32));
}

__global__ void __launch_bounds__(FB_BLOCK)
sampler_fallback(const float* __restrict__ logits, const float* __restrict__ temp_,
                 const float* __restrict__ minp_, const float* __restrict__ topp_,
                 const int* __restrict__ topk_, const float* __restrict__ noise_,
                 float* __restrict__ out, int B, int V, int nlp)
{
  __shared__ FBSM sm;
  const int row = blockIdx.x, tid = threadIdx.x, lane = tid & 63, wv = tid >> 6;
  const float* lrow = logits + (size_t)row * V;
  const float* nrow = noise_ + (size_t)row * V;
  const int V4 = V >> 2, Vt = V4 << 2;
  const float4* l4 = (const float4*)lrow;
  const float4* n4 = (const float4*)nrow;
  for (int i = tid; i < NBINS; i += FB_BLOCK) sm.hist[i] = 0u;
  if (tid == 0) sm.cnt = 0;
  __syncthreads();
  float lmax = -INFINITY;
  for (int i = tid; i < V4; i += FB_BLOCK) {
    float4 v = l4[i]; float a[4] = {v.x, v.y, v.z, v.w};
    #pragma unroll
    for (int c = 0; c < 4; c++) { lmax = fmaxf(lmax, a[c]); atomicAdd(&sm.hist[toOrd(a[c]) >> 19], 1u); }
  }
  for (int i = Vt + tid; i < V; i += FB_BLOCK) {
    float a = lrow[i]; lmax = fmaxf(lmax, a); atomicAdd(&sm.hist[toOrd(a) >> 19], 1u);
  }
  #pragma unroll
  for (int o = 32; o; o >>= 1) lmax = fmaxf(lmax, __shfl_down(lmax, o));
  if (lane == 0) sm.redf[wv] = lmax;
  __syncthreads();
  if (tid == 0) {
    float mm = sm.redf[0];
    for (int w = 1; w < FB_NW; w++) mm = fmaxf(mm, sm.redf[w]);
    sm.m = mm;
    uint32_t cum = 0; int b = NBINS - 1;
    for (; b > 0; b--) { cum += sm.hist[b]; if (cum >= CAND_MIN) break; }
    sm.bstar = b;
  }
  __syncthreads();
  const float m = sm.m;
  const int bstar = sm.bstar;
  const float t = temp_[row];
  const float safe_t = (t < EPSV) ? 1.0f : t;
  const float m_x = m / safe_t;
  float S = 0.f, Sx = 0.f;
  for (int i = tid; i < V4; i += FB_BLOCK) {
    float4 v = l4[i]; float a[4] = {v.x, v.y, v.z, v.w};
    #pragma unroll
    for (int c = 0; c < 4; c++) {
      S += expf(a[c] - m);
      float x = a[c] / safe_t; Sx += expf(x - m_x);
      uint32_t o = toOrd(a[c]);
      if ((int)(o >> 19) >= bstar) {
        int slot = atomicAdd(&sm.cnt, 1);
        if (slot < FB_CAP) sm.cand[slot] = ((uint64_t)(~o) << 32) | (uint32_t)(i * 4 + c);
      }
    }
  }
  for (int i = Vt + tid; i < V; i += FB_BLOCK) {
    float a = lrow[i];
    S += expf(a - m);
    float x = a / safe_t; Sx += expf(x - m_x);
    uint32_t o = toOrd(a);
    if ((int)(o >> 19) >= bstar) {
      int slot = atomicAdd(&sm.cnt, 1);
      if (slot < FB_CAP) sm.cand[slot] = ((uint64_t)(~o) << 32) | (uint32_t)i;
    }
  }
  #pragma unroll
  for (int o = 32; o; o >>= 1) { S += __shfl_down(S, o); Sx += __shfl_down(Sx, o); }
  if (lane == 0) sm.redf[wv] = S;
  __syncthreads();
  if (tid == 0) { float s = 0; for (int w = 0; w < FB_NW; w++) s += sm.redf[w]; sm.S = s; }
  __syncthreads();
  if (lane == 0) sm.redf[wv] = Sx;
  __syncthreads();
  if (tid == 0) { float s = 0; for (int w = 0; w < FB_NW; w++) s += sm.redf[w]; sm.Sx = s; }
  __syncthreads();
  const int count = min(sm.cnt, FB_CAP);
  for (int i = count + tid; i < FB_CAP; i += FB_BLOCK) sm.cand[i] = ~0ull;
  __syncthreads();
  for (int ks = 2; ks <= FB_CAP; ks <<= 1) {
    for (int j = ks >> 1; j > 0; j >>= 1) {
      for (int e = tid; e < FB_CAP; e += FB_BLOCK) {
        int p = e ^ j;
        if (p > e) {
          uint64_t a = sm.cand[e], b2 = sm.cand[p];
          bool up = ((e & ks) == 0);
          if ((a > b2) == up) { sm.cand[e] = b2; sm.cand[p] = a; }
        }
      }
      __syncthreads();
    }
  }
  if (tid == 0) {
    const float Sx_ = sm.Sx;
    const float L = logf(sm.S);
    sm.L = L;
    int i64mode = (B > 1 && topk_[1] == 0) ? 1 : 0;
    int kraw = i64mode ? topk_[2 * row] : topk_[row];
    int k = kraw < 1 ? 1 : (kraw > V ? V : kraw);
    int keff = k < count ? k : count;
    float mpthr = minp_[row] * (1.0f / Sx_);
    sm.mpthr = mpthr;
    float topp = topp_[row];
    int np = 0;
    while (np < keff) {
      float xl = fbCandVal(sm.cand, np) / safe_t;
      float p = expf(xl - m_x) / Sx_;
      if (p < mpthr) break;
      np++;
    }
    float kth_x = NEGV;
    if (np == k) kth_x = fbCandVal(sm.cand, k - 1) / safe_t;
    int kk = np;
    float S2 = 0.f;
    for (int i = 0; i < kk; i++) S2 += expf(fbCandVal(sm.cand, i) / safe_t - m_x);
    float cum = 0.f; int nkeep = 0;
    for (int i = 0; i < kk; i++) {
      float xl = fbCandVal(sm.cand, i) / safe_t;
      float sp = expf(xl - m_x) / S2;
      cum += sp;
      if (cum - sp < topp) nkeep++;
    }
    float cutoff_x = NEGV;
    if (!(cum < topp)) { if (nkeep < 1) nkeep = 1; cutoff_x = fbCandVal(sm.cand, nkeep - 1) / safe_t; }
    sm.kth_x = kth_x; sm.cutoff_x = cutoff_x;
    sm.greedy = (int)(uint32_t)(sm.cand[0] & 0xffffffffu);
  }
  __syncthreads();
  const float kth_x = sm.kth_x, cutoff_x = sm.cutoff_x, mpthr = sm.mpthr, SxR = sm.Sx;
  float bestv = -INFINITY; int besti = 0;
  for (int i = tid; i < V4; i += FB_BLOCK) {
    float4 lv = l4[i]; float4 uv = n4[i];
    float la[4] = {lv.x, lv.y, lv.z, lv.w};
    float ua[4] = {uv.x, uv.y, uv.z, uv.w};
    #pragma unroll
    for (int c = 0; c < 4; c++) {
      float x = la[c] / safe_t;
      float p = expf(x - m_x) / SxR;
      float val = NEGV;
      if (p >= mpthr && x >= kth_x && x >= cutoff_x) val = x + (-logf(-logf(ua[c])));
      if (val > bestv) { bestv = val; besti = i * 4 + c; }
    }
  }
  for (int i = Vt + tid; i < V; i += FB_BLOCK) {
    float x = lrow[i] / safe_t;
    float p = expf(x - m_x) / SxR;
    float val = NEGV;
    if (p >= mpthr && x >= kth_x && x >= cutoff_x) val = x + (-logf(-logf(nrow[i])));
    if (val > bestv) { bestv = val; besti = i; }
  }
  #pragma unroll
  for (int o = 32; o; o >>= 1) {
    float ov = __shfl_down(bestv, o); int oi = __shfl_down(besti, o);
    if (ov > bestv || (ov == bestv && oi < besti)) { bestv = ov; besti = oi; }
  }
  if (lane == 0) { sm.redf[wv] = bestv; sm.redi[wv] = besti; }
  __syncthreads();
  if (tid == 0) {
    float bv = sm.redf[0]; int bi = sm.redi[0];
    for (int w = 1; w < FB_NW; w++) {
      if (sm.redf[w] > bv || (sm.redf[w] == bv && sm.redi[w] < bi)) { bv = sm.redf[w]; bi = sm.redi[w]; }
    }
    int sampled = (t < EPSV) ? sm.greedy : bi;
    float ls = lrow[sampled];
    float token_lp = (ls - m) - sm.L;
    sm.token_lp = token_lp;
    float* out_idx = out + B;
    float* out_lp = out + B + (size_t)B * (1 + nlp);
    size_t rb = (size_t)row * (1 + nlp);
    out[row] = (float)sampled;
    out_idx[rb] = (float)sampled;
    out_lp[rb] = token_lp;
    for (int j = 0; j < nlp; j++) {
      uint64_t cdv = sm.cand[j];
      out_idx[rb + 1 + j] = (float)(int)(uint32_t)(cdv & 0xffffffffu);
      out_lp[rb + 1 + j] = (fromOrd(~(uint32_t)(cdv >> 32)) - m) - sm.L;
    }
  }
  __syncthreads();
  const float Lc = sm.L, tlp = sm.token_lp;
  int cnt = 0;
  for (int i = tid; i < V4; i += FB_BLOCK) {
    float4 v = l4[i]; float a[4] = {v.x, v.y, v.z, v.w};
    #pragma unroll
    for (int c = 0; c < 4; c++) { float lp = (a[c] - m) - Lc; cnt += (lp >= tlp) ? 1 : 0; }
  }
  for (int i = Vt + tid; i < V; i += FB_BLOCK) {
    float lp = (lrow[i] - m) - Lc; cnt += (lp >= tlp) ? 1 : 0;
  }
  #pragma unroll
  for (int o = 32; o; o >>= 1) cnt += __shfl_down(cnt, o);
  if (lane == 0) sm.redi[wv] = cnt;
  __syncthreads();
  if (tid == 0) {
    int r = 0;
    for (int w = 0; w < FB_NW; w++) r += sm.redi[w];
    out[B + 2 * (size_t)B * (1 + nlp) + row] = (float)r;
  }
}

extern "C" void kernel_launch(void* const* d_in, const int* in_sizes, int n_in,
                              void* d_out, int out_size, void* d_ws, size_t ws_size,
                              hipStream_t stream) {
  const float* logits = (const float*)d_in[0];
  const float* temp   = (const float*)d_in[1];
  const float* minp   = (const float*)d_in[2];
  const float* topp   = (const float*)d_in[3];
  const int*   topk   = (const int*)d_in[4];
  const float* noise  = (const float*)d_in[5];
  int B = in_sizes[1];
  int V = in_sizes[0] / B;
  int nlp = (out_size / B - 4) / 2;
  if (nlp < 0) nlp = 0;

  uint8_t* ws = (uint8_t*)d_ws;
  size_t off = 0;
  uint32_t* ccnt = (uint32_t*)(ws + off); off += (size_t)B * 4;
  size_t zeroBytes = off;
  float* pmax = (float*)(ws + off); off += (size_t)B * NS * 4;
  float* pS   = (float*)(ws + off); off += (size_t)B * NS * 4;
  float* pSx  = (float*)(ws + off); off += (size_t)B * NS * 4;
  off = (off + 7) & ~(size_t)7;
  uint64_t* cand = (uint64_t*)(ws + off); off += (size_t)B * CANDC * 8;

  // capacity check: register cache must cover the chunk
  const int clen = ((V + NS - 1) / NS + 3) & ~3;
  bool fits = (clen <= K3B * 8 * 4) && ((V & 3) == 0);

  if (ws_size < off || !fits) {
    hipLaunchKernelGGL(sampler_fallback, dim3(B), dim3(FB_BLOCK), 0, stream,
                       logits, temp, minp, topp, topk, noise, (float*)d_out, B, V, nlp);
    return;
  }

  hipMemsetAsync(d_ws, 0, zeroBytes, stream);
  hipLaunchKernelGGL(k3_fused, dim3(NS, B), dim3(K3B), 0, stream,
                     logits, temp, pmax, pS, pSx, ccnt, cand, V);
  hipLaunchKernelGGL(k4_final, dim3(B), dim3(1024), 0, stream,
                     temp, minp, topp, topk, noise, pmax, pS, pSx, ccnt, cand,
                     (float*)d_out, B, V, nlp);
}

// Round 5
// 259.985 us; speedup vs baseline: 2.6856x; 2.6856x over previous
//
#include <hip/hip_runtime.h>
#include <stdint.h>
#include <math.h>

#define NS 8
#define K3B 512
#define NBINS 8192
#define SEG 320
#define CANDC 4096
#define CAND_MIN 128
#define NEGV -1e30f
#define EPSV 1e-5f

__device__ __forceinline__ uint32_t toOrd(float f) {
  uint32_t u = __float_as_uint(f);
  return (u & 0x80000000u) ? ~u : (u | 0x80000000u);
}
__device__ __forceinline__ float fromOrd(uint32_t o) {
  uint32_t u = (o & 0x80000000u) ? (o & 0x7fffffffu) : ~o;
  return __uint_as_float(u);
}

// ---- K3: per-(row,chunk): hist+max -> bstar -> S/Sx + private candidate collect ----
__global__ void __launch_bounds__(K3B)
k3_fused(const float* __restrict__ logits, const float* __restrict__ temp_,
         float* __restrict__ pmax, float* __restrict__ pS, float* __restrict__ pSx,
         uint32_t* __restrict__ pcnt, uint64_t* __restrict__ cand, int V)
{
  const int chunk = blockIdx.x, row = blockIdx.y;
  const int tid = threadIdx.x, lane = tid & 63, wv = tid >> 6;
  __shared__ uint32_t h[NBINS];
  __shared__ uint32_t sfx[K3B + 1];
  __shared__ float redf[8], redf2[8];
  __shared__ int s_gsel, s_bstar;
  __shared__ float s_m;
  __shared__ uint32_t s_loc;
  __shared__ uint64_t stage[SEG];

  for (int i = tid; i < NBINS; i += K3B) h[i] = 0u;
  if (tid == 0) { s_loc = 0u; s_gsel = 0; }
  __syncthreads();

  const int clen = ((V + NS - 1) / NS + 3) & ~3;
  const int start = chunk * clen;
  int valid = V - start;
  if (valid < 0) valid = 0;
  if (valid > clen) valid = clen;
  const int nf4 = valid >> 2;
  const float* crow = logits + (size_t)row * V + start;
  const float4* p4 = (const float4*)crow;

  // ---- pass A: chunk max + LDS histogram ----
  float lmax = -INFINITY;
  for (int i = tid; i < nf4; i += K3B) {
    float4 v = p4[i];
    float a[4] = {v.x, v.y, v.z, v.w};
    #pragma unroll
    for (int c = 0; c < 4; c++) {
      lmax = fmaxf(lmax, a[c]);
      atomicAdd(&h[toOrd(a[c]) >> 19], 1u);
    }
  }
  for (int i = (nf4 << 2) + tid; i < valid; i += K3B) {
    float a = crow[i];
    lmax = fmaxf(lmax, a);
    atomicAdd(&h[toOrd(a) >> 19], 1u);
  }
  #pragma unroll
  for (int o = 32; o; o >>= 1) lmax = fmaxf(lmax, __shfl_down(lmax, o));
  if (lane == 0) redf[wv] = lmax;
  __syncthreads();

  // ---- suffix scan over 512 groups of 16 bins -> bstar ----
  {
    uint32_t g = 0;
    #pragma unroll
    for (int b = 0; b < 16; b++) g += h[tid * 16 + b];
    sfx[tid] = g;
    if (tid == 0) sfx[K3B] = 0;
    __syncthreads();
    for (int off = 1; off < K3B; off <<= 1) {
      uint32_t v = (tid + off < K3B) ? sfx[tid + off] : 0u;
      __syncthreads();
      sfx[tid] += v;
      __syncthreads();
    }
    uint32_t gs = sfx[tid], gn = sfx[tid + 1];
    if (gs >= CAND_MIN && gn < CAND_MIN) s_gsel = tid;
    __syncthreads();
  }
  if (tid == 0) {
    int gsl = s_gsel;
    uint32_t cum = sfx[gsl + 1];
    int bsel = gsl * 16;
    for (int b = gsl * 16 + 15; b >= gsl * 16; b--) {
      cum += h[b];
      if (cum >= CAND_MIN) { bsel = b; break; }
    }
    s_bstar = bsel;
    float mm = redf[0];
    for (int w = 1; w < 8; w++) mm = fmaxf(mm, redf[w]);
    s_m = mm;
    pmax[row * NS + chunk] = mm;
  }
  __syncthreads();

  const float m_c = s_m;
  const int bst = s_bstar;
  const float t = temp_[row];
  const float safe_t = (t < EPSV) ? 1.0f : t;
  const float m_xc = m_c / safe_t;

  // ---- pass B (L2 re-read): chunk-local sums + LDS-private candidate collect ----
  float S = 0.f, Sx = 0.f;
  for (int i = tid; i < nf4; i += K3B) {
    float4 v = p4[i];
    float a[4] = {v.x, v.y, v.z, v.w};
    #pragma unroll
    for (int c = 0; c < 4; c++) {
      S += expf(a[c] - m_c);
      float x = a[c] / safe_t;
      Sx += expf(x - m_xc);
      uint32_t o = toOrd(a[c]);
      if ((int)(o >> 19) >= bst) {
        uint32_t slot = atomicAdd(&s_loc, 1u);
        if (slot < SEG)
          stage[slot] = ((uint64_t)(~o) << 32) | (uint32_t)(start + i * 4 + c);
      }
    }
  }
  for (int i = (nf4 << 2) + tid; i < valid; i += K3B) {
    float a = crow[i];
    S += expf(a - m_c);
    float x = a / safe_t;
    Sx += expf(x - m_xc);
    uint32_t o = toOrd(a);
    if ((int)(o >> 19) >= bst) {
      uint32_t slot = atomicAdd(&s_loc, 1u);
      if (slot < SEG)
        stage[slot] = ((uint64_t)(~o) << 32) | (uint32_t)(start + i);
    }
  }
  #pragma unroll
  for (int o = 32; o; o >>= 1) { S += __shfl_down(S, o); Sx += __shfl_down(Sx, o); }
  if (lane == 0) { redf[wv] = S; redf2[wv] = Sx; }
  __syncthreads();
  if (tid == 0) {
    float s = 0, sx = 0;
    for (int w = 0; w < 8; w++) { s += redf[w]; sx += redf2[w]; }
    pS[row * NS + chunk] = s;
    pSx[row * NS + chunk] = sx;
  }
  // flush private segment (plain stores, no global atomics)
  int lc = (int)s_loc; if (lc > SEG) lc = SEG;
  for (int i = tid; i < lc; i += K3B)
    cand[((size_t)row * NS + chunk) * SEG + i] = stage[i];
  if (tid == 0) pcnt[row * NS + chunk] = (uint32_t)lc;
}

// ---- K4: gather segments, sort, cutoffs, gumbel argmax, rank, outputs ----
__global__ void __launch_bounds__(1024)
k4_final(const float* __restrict__ temp_, const float* __restrict__ minp_,
         const float* __restrict__ topp_, const int* __restrict__ topk_,
         const float* __restrict__ noise_,
         const float* __restrict__ pmax, const float* __restrict__ pS,
         const float* __restrict__ pSx, const uint32_t* __restrict__ pcnt,
         const uint64_t* __restrict__ candG, float* __restrict__ out,
         int B, int V, int nlp)
{
  const int row = blockIdx.x, tid = threadIdx.x, lane = tid & 63, wv = tid >> 6;
  __shared__ uint64_t cd[CANDC];
  __shared__ int soff[NS + 1];
  __shared__ float redv[16], redl[16];
  __shared__ int redi[16], redr[16];
  __shared__ float sh_kth, sh_cut, sh_mpthr, sh_m, sh_L, sh_safe_t, sh_mx, sh_Sx, sh_tlp;

  if (tid == 0) {
    int o = 0;
    for (int c = 0; c < NS; c++) {
      soff[c] = o;
      int cc = (int)pcnt[row * NS + c];
      if (cc > SEG) cc = SEG;
      o += cc;
    }
    soff[NS] = o;
  }
  __syncthreads();
  const int total = soff[NS];
  for (int idx = tid; idx < NS * SEG; idx += 1024) {
    int c = idx / SEG, i = idx - c * SEG;
    int cc = soff[c + 1] - soff[c];
    if (i < cc) cd[soff[c] + i] = candG[((size_t)row * NS + c) * SEG + i];
  }
  for (int idx = total + tid; idx < CANDC; idx += 1024) cd[idx] = ~0ull;
  __syncthreads();

  // bitonic sort ascending on key (~ord<<32 | idx) => value desc, idx asc
  for (int ks = 2; ks <= CANDC; ks <<= 1) {
    for (int j = ks >> 1; j; j >>= 1) {
      for (int e = tid; e < CANDC; e += 1024) {
        int p = e ^ j;
        if (p > e) {
          uint64_t a = cd[e], b = cd[p];
          bool up = ((e & ks) == 0);
          if ((a > b) == up) { cd[e] = b; cd[p] = a; }
        }
      }
      __syncthreads();
    }
  }

  if (tid == 0) {
    float t = temp_[row];
    float safe_t = (t < EPSV) ? 1.0f : t;
    float m = pmax[row * NS + 0];
    for (int c = 1; c < NS; c++) m = fmaxf(m, pmax[row * NS + c]);
    float m_x = m / safe_t;
    float S = 0, Sx = 0;
    for (int c = 0; c < NS; c++) {
      float mc = pmax[row * NS + c];
      S  += pS[row * NS + c]  * expf(mc - m);
      Sx += pSx[row * NS + c] * expf(mc / safe_t - m_x);
    }
    float L = logf(S);
    int i64mode = (B > 1 && topk_[1] == 0) ? 1 : 0;
    int kraw = i64mode ? topk_[2 * row] : topk_[row];
    int k = kraw < 1 ? 1 : (kraw > V ? V : kraw);
    int keff = k < total ? k : total;
    float mpthr = minp_[row] * (1.0f / Sx);
    float topp = topp_[row];
    int np = 0;
    while (np < keff) {
      float xl = fromOrd(~(uint32_t)(cd[np] >> 32)) / safe_t;
      float p = expf(xl - m_x) / Sx;
      if (p < mpthr) break;
      np++;
    }
    float kth_x = NEGV;
    if (np == k) kth_x = fromOrd(~(uint32_t)(cd[k - 1] >> 32)) / safe_t;
    int kk = np;
    float S2 = 0.f;
    for (int i = 0; i < kk; i++)
      S2 += expf(fromOrd(~(uint32_t)(cd[i] >> 32)) / safe_t - m_x);
    float cum = 0.f; int nkeep = 0;
    for (int i = 0; i < kk; i++) {
      float xl = fromOrd(~(uint32_t)(cd[i] >> 32)) / safe_t;
      float sp = expf(xl - m_x) / S2;
      cum += sp;
      if (cum - sp < topp) nkeep++;
    }
    float cutoff_x = NEGV;
    if (!(cum < topp)) {
      if (nkeep < 1) nkeep = 1;
      cutoff_x = fromOrd(~(uint32_t)(cd[nkeep - 1] >> 32)) / safe_t;
    }
    sh_kth = kth_x; sh_cut = cutoff_x; sh_mpthr = mpthr; sh_m = m; sh_L = L;
    sh_safe_t = safe_t; sh_mx = m_x; sh_Sx = Sx;
  }
  __syncthreads();

  // gumbel argmax over kept candidates (scattered noise reads, <=k per row)
  float bestv = -INFINITY, bestl = 0.f; int besti = 0x7fffffff;
  for (int e = tid; e < total; e += 1024) {
    uint64_t c = cd[e];
    float l = fromOrd(~(uint32_t)(c >> 32));
    int idx = (int)(uint32_t)(c & 0xffffffffu);
    float x = l / sh_safe_t;
    float p = expf(x - sh_mx) / sh_Sx;
    if (p >= sh_mpthr && x >= sh_kth && x >= sh_cut) {
      float u = noise_[(size_t)row * V + idx];
      float v = x + (-logf(-logf(u)));
      if (v > bestv || (v == bestv && idx < besti)) { bestv = v; besti = idx; bestl = l; }
    }
  }
  #pragma unroll
  for (int o = 32; o; o >>= 1) {
    float ov = __shfl_down(bestv, o); int oi = __shfl_down(besti, o); float ol = __shfl_down(bestl, o);
    if (ov > bestv || (ov == bestv && oi < besti)) { bestv = ov; besti = oi; bestl = ol; }
  }
  if (lane == 0) { redv[wv] = bestv; redi[wv] = besti; redl[wv] = bestl; }
  __syncthreads();
  if (tid == 0) {
    float bv = redv[0]; int bi = redi[0]; float bl = redl[0];
    for (int w = 1; w < 16; w++) {
      if (redv[w] > bv || (redv[w] == bv && redi[w] < bi)) { bv = redv[w]; bi = redi[w]; bl = redl[w]; }
    }
    float t = temp_[row];
    int sampled; float ls;
    if (t < EPSV) {
      uint64_t c0 = cd[0];
      sampled = (int)(uint32_t)(c0 & 0xffffffffu);
      ls = fromOrd(~(uint32_t)(c0 >> 32));
    } else { sampled = bi; ls = bl; }
    float token_lp = (ls - sh_m) - sh_L;
    sh_tlp = token_lp;
    float* out_idx = out + B;
    float* out_lp = out + B + (size_t)B * (1 + nlp);
    size_t rb = (size_t)row * (1 + nlp);
    out[row] = (float)sampled;
    out_idx[rb] = (float)sampled;
    out_lp[rb] = token_lp;
    for (int j = 0; j < nlp; j++) {
      uint64_t c = cd[j];
      out_idx[rb + 1 + j] = (float)(int)(uint32_t)(c & 0xffffffffu);
      out_lp[rb + 1 + j] = (fromOrd(~(uint32_t)(c >> 32)) - sh_m) - sh_L;
    }
  }
  __syncthreads();

  // rank over candidates (any element >= sampled's logit is provably a candidate)
  int rc = 0;
  for (int e = tid; e < total; e += 1024) {
    float l = fromOrd(~(uint32_t)(cd[e] >> 32));
    float f = (l - sh_m) - sh_L;
    rc += (f >= sh_tlp) ? 1 : 0;
  }
  #pragma unroll
  for (int o = 32; o; o >>= 1) rc += __shfl_down(rc, o);
  if (lane == 0) redr[wv] = rc;
  __syncthreads();
  if (tid == 0) {
    int r = 0;
    for (int w = 0; w < 16; w++) r += redr[w];
    out[B + 2 * (size_t)B * (1 + nlp) + row] = (float)r;
  }
}

// ================= fallback: proven monolithic kernel (R2, passed) =================
#define FB_BLOCK 1024
#define FB_CAP 2048
#define FB_NW 16

struct FBSM {
  uint32_t hist[NBINS];
  uint64_t cand[FB_CAP];
  float redf[FB_NW];
  int   redi[FB_NW];
  int cnt; int bstar;
  float m, S, Sx;
  float kth_x, cutoff_x, mpthr;
  float L, token_lp;
  int greedy;
};

__device__ __forceinline__ float fbCandVal(const uint64_t* cand, int i) {
  return fromOrd(~(uint32_t)(cand[i] >> 32));
}

__global__ void __launch_bounds__(FB_BLOCK)
sampler_fallback(const float* __restrict__ logits, const float* __restrict__ temp_,
                 const float* __restrict__ minp_, const float* __restrict__ topp_,
                 const int* __restrict__ topk_, const float* __restrict__ noise_,
                 float* __restrict__ out, int B, int V, int nlp)
{
  __shared__ FBSM sm;
  const int row = blockIdx.x, tid = threadIdx.x, lane = tid & 63, wv = tid >> 6;
  const float* lrow = logits + (size_t)row * V;
  const float* nrow = noise_ + (size_t)row * V;
  const int V4 = V >> 2, Vt = V4 << 2;
  const float4* l4 = (const float4*)lrow;
  const float4* n4 = (const float4*)nrow;
  for (int i = tid; i < NBINS; i += FB_BLOCK) sm.hist[i] = 0u;
  if (tid == 0) sm.cnt = 0;
  __syncthreads();
  float lmax = -INFINITY;
  for (int i = tid; i < V4; i += FB_BLOCK) {
    float4 v = l4[i]; float a[4] = {v.x, v.y, v.z, v.w};
    #pragma unroll
    for (int c = 0; c < 4; c++) { lmax = fmaxf(lmax, a[c]); atomicAdd(&sm.hist[toOrd(a[c]) >> 19], 1u); }
  }
  for (int i = Vt + tid; i < V; i += FB_BLOCK) {
    float a = lrow[i]; lmax = fmaxf(lmax, a); atomicAdd(&sm.hist[toOrd(a) >> 19], 1u);
  }
  #pragma unroll
  for (int o = 32; o; o >>= 1) lmax = fmaxf(lmax, __shfl_down(lmax, o));
  if (lane == 0) sm.redf[wv] = lmax;
  __syncthreads();
  if (tid == 0) {
    float mm = sm.redf[0];
    for (int w = 1; w < FB_NW; w++) mm = fmaxf(mm, sm.redf[w]);
    sm.m = mm;
    uint32_t cum = 0; int b = NBINS - 1;
    for (; b > 0; b--) { cum += sm.hist[b]; if (cum >= CAND_MIN) break; }
    sm.bstar = b;
  }
  __syncthreads();
  const float m = sm.m;
  const int bstar = sm.bstar;
  const float t = temp_[row];
  const float safe_t = (t < EPSV) ? 1.0f : t;
  const float m_x = m / safe_t;
  float S = 0.f, Sx = 0.f;
  for (int i = tid; i < V4; i += FB_BLOCK) {
    float4 v = l4[i]; float a[4] = {v.x, v.y, v.z, v.w};
    #pragma unroll
    for (int c = 0; c < 4; c++) {
      S += expf(a[c] - m);
      float x = a[c] / safe_t; Sx += expf(x - m_x);
      uint32_t o = toOrd(a[c]);
      if ((int)(o >> 19) >= bstar) {
        int slot = atomicAdd(&sm.cnt, 1);
        if (slot < FB_CAP) sm.cand[slot] = ((uint64_t)(~o) << 32) | (uint32_t)(i * 4 + c);
      }
    }
  }
  for (int i = Vt + tid; i < V; i += FB_BLOCK) {
    float a = lrow[i];
    S += expf(a - m);
    float x = a / safe_t; Sx += expf(x - m_x);
    uint32_t o = toOrd(a);
    if ((int)(o >> 19) >= bstar) {
      int slot = atomicAdd(&sm.cnt, 1);
      if (slot < FB_CAP) sm.cand[slot] = ((uint64_t)(~o) << 32) | (uint32_t)i;
    }
  }
  #pragma unroll
  for (int o = 32; o; o >>= 1) { S += __shfl_down(S, o); Sx += __shfl_down(Sx, o); }
  if (lane == 0) sm.redf[wv] = S;
  __syncthreads();
  if (tid == 0) { float s = 0; for (int w = 0; w < FB_NW; w++) s += sm.redf[w]; sm.S = s; }
  __syncthreads();
  if (lane == 0) sm.redf[wv] = Sx;
  __syncthreads();
  if (tid == 0) { float s = 0; for (int w = 0; w < FB_NW; w++) s += sm.redf[w]; sm.Sx = s; }
  __syncthreads();
  const int count = min(sm.cnt, FB_CAP);
  for (int i = count + tid; i < FB_CAP; i += FB_BLOCK) sm.cand[i] = ~0ull;
  __syncthreads();
  for (int ks = 2; ks <= FB_CAP; ks <<= 1) {
    for (int j = ks >> 1; j > 0; j >>= 1) {
      for (int e = tid; e < FB_CAP; e += FB_BLOCK) {
        int p = e ^ j;
        if (p > e) {
          uint64_t a = sm.cand[e], b2 = sm.cand[p];
          bool up = ((e & ks) == 0);
          if ((a > b2) == up) { sm.cand[e] = b2; sm.cand[p] = a; }
        }
      }
      __syncthreads();
    }
  }
  if (tid == 0) {
    const float Sx_ = sm.Sx;
    const float L = logf(sm.S);
    sm.L = L;
    int i64mode = (B > 1 && topk_[1] == 0) ? 1 : 0;
    int kraw = i64mode ? topk_[2 * row] : topk_[row];
    int k = kraw < 1 ? 1 : (kraw > V ? V : kraw);
    int keff = k < count ? k : count;
    float mpthr = minp_[row] * (1.0f / Sx_);
    sm.mpthr = mpthr;
    float topp = topp_[row];
    int np = 0;
    while (np < keff) {
      float xl = fbCandVal(sm.cand, np) / safe_t;
      float p = expf(xl - m_x) / Sx_;
      if (p < mpthr) break;
      np++;
    }
    float kth_x = NEGV;
    if (np == k) kth_x = fbCandVal(sm.cand, k - 1) / safe_t;
    int kk = np;
    float S2 = 0.f;
    for (int i = 0; i < kk; i++) S2 += expf(fbCandVal(sm.cand, i) / safe_t - m_x);
    float cum = 0.f; int nkeep = 0;
    for (int i = 0; i < kk; i++) {
      float xl = fbCandVal(sm.cand, i) / safe_t;
      float sp = expf(xl - m_x) / S2;
      cum += sp;
      if (cum - sp < topp) nkeep++;
    }
    float cutoff_x = NEGV;
    if (!(cum < topp)) { if (nkeep < 1) nkeep = 1; cutoff_x = fbCandVal(sm.cand, nkeep - 1) / safe_t; }
    sm.kth_x = kth_x; sm.cutoff_x = cutoff_x;
    sm.greedy = (int)(uint32_t)(sm.cand[0] & 0xffffffffu);
  }
  __syncthreads();
  const float kth_x = sm.kth_x, cutoff_x = sm.cutoff_x, mpthr = sm.mpthr, SxR = sm.Sx;
  float bestv = -INFINITY; int besti = 0;
  for (int i = tid; i < V4; i += FB_BLOCK) {
    float4 lv = l4[i]; float4 uv = n4[i];
    float la[4] = {lv.x, lv.y, lv.z, lv.w};
    float ua[4] = {uv.x, uv.y, uv.z, uv.w};
    #pragma unroll
    for (int c = 0; c < 4; c++) {
      float x = la[c] / safe_t;
      float p = expf(x - m_x) / SxR;
      float val = NEGV;
      if (p >= mpthr && x >= kth_x && x >= cutoff_x) val = x + (-logf(-logf(ua[c])));
      if (val > bestv) { bestv = val; besti = i * 4 + c; }
    }
  }
  for (int i = Vt + tid; i < V; i += FB_BLOCK) {
    float x = lrow[i] / safe_t;
    float p = expf(x - m_x) / SxR;
    float val = NEGV;
    if (p >= mpthr && x >= kth_x && x >= cutoff_x) val = x + (-logf(-logf(nrow[i])));
    if (val > bestv) { bestv = val; besti = i; }
  }
  #pragma unroll
  for (int o = 32; o; o >>= 1) {
    float ov = __shfl_down(bestv, o); int oi = __shfl_down(besti, o);
    if (ov > bestv || (ov == bestv && oi < besti)) { bestv = ov; besti = oi; }
  }
  if (lane == 0) { sm.redf[wv] = bestv; sm.redi[wv] = besti; }
  __syncthreads();
  if (tid == 0) {
    float bv = sm.redf[0]; int bi = sm.redi[0];
    for (int w = 1; w < FB_NW; w++) {
      if (sm.redf[w] > bv || (sm.redf[w] == bv && sm.redi[w] < bi)) { bv = sm.redf[w]; bi = sm.redi[w]; }
    }
    int sampled = (t < EPSV) ? sm.greedy : bi;
    float ls = lrow[sampled];
    float token_lp = (ls - m) - sm.L;
    sm.token_lp = token_lp;
    float* out_idx = out + B;
    float* out_lp = out + B + (size_t)B * (1 + nlp);
    size_t rb = (size_t)row * (1 + nlp);
    out[row] = (float)sampled;
    out_idx[rb] = (float)sampled;
    out_lp[rb] = token_lp;
    for (int j = 0; j < nlp; j++) {
      uint64_t cdv = sm.cand[j];
      out_idx[rb + 1 + j] = (float)(int)(uint32_t)(cdv & 0xffffffffu);
      out_lp[rb + 1 + j] = (fromOrd(~(uint32_t)(cdv >> 32)) - m) - sm.L;
    }
  }
  __syncthreads();
  const float Lc = sm.L, tlp = sm.token_lp;
  int cnt = 0;
  for (int i = tid; i < V4; i += FB_BLOCK) {
    float4 v = l4[i]; float a[4] = {v.x, v.y, v.z, v.w};
    #pragma unroll
    for (int c = 0; c < 4; c++) { float lp = (a[c] - m) - Lc; cnt += (lp >= tlp) ? 1 : 0; }
  }
  for (int i = Vt + tid; i < V; i += FB_BLOCK) {
    float lp = (lrow[i] - m) - Lc; cnt += (lp >= tlp) ? 1 : 0;
  }
  #pragma unroll
  for (int o = 32; o; o >>= 1) cnt += __shfl_down(cnt, o);
  if (lane == 0) sm.redi[wv] = cnt;
  __syncthreads();
  if (tid == 0) {
    int r = 0;
    for (int w = 0; w < FB_NW; w++) r += sm.redi[w];
    out[B + 2 * (size_t)B * (1 + nlp) + row] = (float)r;
  }
}

extern "C" void kernel_launch(void* const* d_in, const int* in_sizes, int n_in,
                              void* d_out, int out_size, void* d_ws, size_t ws_size,
                              hipStream_t stream) {
  const float* logits = (const float*)d_in[0];
  const float* temp   = (const float*)d_in[1];
  const float* minp   = (const float*)d_in[2];
  const float* topp   = (const float*)d_in[3];
  const int*   topk   = (const int*)d_in[4];
  const float* noise  = (const float*)d_in[5];
  int B = in_sizes[1];
  int V = in_sizes[0] / B;
  int nlp = (out_size / B - 4) / 2;
  if (nlp < 0) nlp = 0;

  uint8_t* ws = (uint8_t*)d_ws;
  size_t off = 0;
  uint32_t* pcnt = (uint32_t*)(ws + off); off += (size_t)B * NS * 4;
  float* pmax = (float*)(ws + off); off += (size_t)B * NS * 4;
  float* pS   = (float*)(ws + off); off += (size_t)B * NS * 4;
  float* pSx  = (float*)(ws + off); off += (size_t)B * NS * 4;
  off = (off + 7) & ~(size_t)7;
  uint64_t* cand = (uint64_t*)(ws + off); off += (size_t)B * NS * SEG * 8;

  if (ws_size < off) {
    hipLaunchKernelGGL(sampler_fallback, dim3(B), dim3(FB_BLOCK), 0, stream,
                       logits, temp, minp, topp, topk, noise, (float*)d_out, B, V, nlp);
    return;
  }

  hipLaunchKernelGGL(k3_fused, dim3(NS, B), dim3(K3B), 0, stream,
                     logits, temp, pmax, pS, pSx, pcnt, cand, V);
  hipLaunchKernelGGL(k4_final, dim3(B), dim3(1024), 0, stream,
                     temp, minp, topp, topk, noise, pmax, pS, pSx, pcnt, cand,
                     (float*)d_out, B, V, nlp);
}

// Round 8
// 222.439 us; speedup vs baseline: 3.1389x; 1.1688x over previous
//
#include <hip/hip_runtime.h>
#include <stdint.h>
#include <math.h>

#define NS 8
#define K3B 512
#define K4B 256
#define NBINS 8192
#define SEG 320
#define CANDC 4096
#define CAND_MIN 128
#define NEGV -1e30f
#define EPSV 1e-5f

__device__ __forceinline__ uint32_t toOrd(float f) {
  uint32_t u = __float_as_uint(f);
  return (u & 0x80000000u) ? ~u : (u | 0x80000000u);
}
__device__ __forceinline__ float fromOrd(uint32_t o) {
  uint32_t u = (o & 0x80000000u) ? (o & 0x7fffffffu) : ~o;
  return __uint_as_float(u);
}

// ---- K3: per-(row,chunk): hist+max -> bstar -> S/Sx + private candidate collect ----
__global__ void __launch_bounds__(K3B)
k3_fused(const float* __restrict__ logits, const float* __restrict__ temp_,
         float* __restrict__ pmax, float* __restrict__ pS, float* __restrict__ pSx,
         uint32_t* __restrict__ pcnt, uint64_t* __restrict__ cand, int V)
{
  const int chunk = blockIdx.x, row = blockIdx.y;
  const int tid = threadIdx.x, lane = tid & 63, wv = tid >> 6;
  __shared__ uint32_t h[NBINS];
  __shared__ uint32_t sfx[K3B + 1];
  __shared__ float redf[8], redf2[8];
  __shared__ int s_gsel, s_bstar;
  __shared__ float s_m;
  __shared__ uint32_t s_loc;
  __shared__ uint64_t stage[SEG];

  for (int i = tid; i < NBINS; i += K3B) h[i] = 0u;
  if (tid == 0) { s_loc = 0u; s_gsel = 0; }
  __syncthreads();

  const int clen = ((V + NS - 1) / NS + 3) & ~3;
  const int start = chunk * clen;
  int valid = V - start;
  if (valid < 0) valid = 0;
  if (valid > clen) valid = clen;
  const int nf4 = valid >> 2;
  const float* crow = logits + (size_t)row * V + start;
  const float4* p4 = (const float4*)crow;

  // ---- pass A: chunk max + LDS histogram ----
  float lmax = -INFINITY;
  for (int i = tid; i < nf4; i += K3B) {
    float4 v = p4[i];
    float a[4] = {v.x, v.y, v.z, v.w};
    #pragma unroll
    for (int c = 0; c < 4; c++) {
      lmax = fmaxf(lmax, a[c]);
      atomicAdd(&h[toOrd(a[c]) >> 19], 1u);
    }
  }
  for (int i = (nf4 << 2) + tid; i < valid; i += K3B) {
    float a = crow[i];
    lmax = fmaxf(lmax, a);
    atomicAdd(&h[toOrd(a) >> 19], 1u);
  }
  #pragma unroll
  for (int o = 32; o; o >>= 1) lmax = fmaxf(lmax, __shfl_down(lmax, o));
  if (lane == 0) redf[wv] = lmax;
  __syncthreads();

  // ---- suffix scan over 512 groups of 16 bins -> bstar ----
  {
    uint32_t g = 0;
    #pragma unroll
    for (int b = 0; b < 16; b++) g += h[tid * 16 + b];
    sfx[tid] = g;
    if (tid == 0) sfx[K3B] = 0;
    __syncthreads();
    for (int off = 1; off < K3B; off <<= 1) {
      uint32_t v = (tid + off < K3B) ? sfx[tid + off] : 0u;
      __syncthreads();
      sfx[tid] += v;
      __syncthreads();
    }
    uint32_t gs = sfx[tid], gn = sfx[tid + 1];
    if (gs >= CAND_MIN && gn < CAND_MIN) s_gsel = tid;
    __syncthreads();
  }
  if (tid == 0) {
    int gsl = s_gsel;
    uint32_t cum = sfx[gsl + 1];
    int bsel = gsl * 16;
    for (int b = gsl * 16 + 15; b >= gsl * 16; b--) {
      cum += h[b];
      if (cum >= CAND_MIN) { bsel = b; break; }
    }
    s_bstar = bsel;
    float mm = redf[0];
    for (int w = 1; w < 8; w++) mm = fmaxf(mm, redf[w]);
    s_m = mm;
    pmax[row * NS + chunk] = mm;
  }
  __syncthreads();

  const float m_c = s_m;
  const int bst = s_bstar;
  const float t = temp_[row];
  const float safe_t = (t < EPSV) ? 1.0f : t;
  const float m_xc = m_c / safe_t;

  // ---- pass B (L2 re-read): chunk-local sums + LDS-private candidate collect ----
  float S = 0.f, Sx = 0.f;
  for (int i = tid; i < nf4; i += K3B) {
    float4 v = p4[i];
    float a[4] = {v.x, v.y, v.z, v.w};
    #pragma unroll
    for (int c = 0; c < 4; c++) {
      S += expf(a[c] - m_c);
      float x = a[c] / safe_t;
      Sx += expf(x - m_xc);
      uint32_t o = toOrd(a[c]);
      if ((int)(o >> 19) >= bst) {
        uint32_t slot = atomicAdd(&s_loc, 1u);
        if (slot < SEG)
          stage[slot] = ((uint64_t)(~o) << 32) | (uint32_t)(start + i * 4 + c);
      }
    }
  }
  for (int i = (nf4 << 2) + tid; i < valid; i += K3B) {
    float a = crow[i];
    S += expf(a - m_c);
    float x = a / safe_t;
    Sx += expf(x - m_xc);
    uint32_t o = toOrd(a);
    if ((int)(o >> 19) >= bst) {
      uint32_t slot = atomicAdd(&s_loc, 1u);
      if (slot < SEG)
        stage[slot] = ((uint64_t)(~o) << 32) | (uint32_t)(start + i);
    }
  }
  #pragma unroll
  for (int o = 32; o; o >>= 1) { S += __shfl_down(S, o); Sx += __shfl_down(Sx, o); }
  if (lane == 0) { redf[wv] = S; redf2[wv] = Sx; }
  __syncthreads();
  if (tid == 0) {
    float s = 0, sx = 0;
    for (int w = 0; w < 8; w++) { s += redf[w]; sx += redf2[w]; }
    pS[row * NS + chunk] = s;
    pSx[row * NS + chunk] = sx;
  }
  // flush private segment (plain stores, no global atomics)
  int lc = (int)s_loc; if (lc > SEG) lc = SEG;
  for (int i = tid; i < lc; i += K3B)
    cand[((size_t)row * NS + chunk) * SEG + i] = stage[i];
  if (tid == 0) pcnt[row * NS + chunk] = (uint32_t)lc;
}

// ---- K4: gather, PRUNE to global top-~128, small sort, cutoffs, gumbel, rank ----
__global__ void __launch_bounds__(K4B)
k4_final(const float* __restrict__ temp_, const float* __restrict__ minp_,
         const float* __restrict__ topp_, const int* __restrict__ topk_,
         const float* __restrict__ noise_,
         const float* __restrict__ pmax, const float* __restrict__ pS,
         const float* __restrict__ pSx, const uint32_t* __restrict__ pcnt,
         const uint64_t* __restrict__ candG, float* __restrict__ out,
         int B, int V, int nlp)
{
  const int row = blockIdx.x, tid = threadIdx.x, lane = tid & 63, wv = tid >> 6;
  __shared__ uint64_t cd[CANDC];
  __shared__ uint64_t cd2[CANDC];
  __shared__ uint32_t h[NBINS];
  __shared__ uint32_t sfx[K4B + 1];
  __shared__ int soff[NS + 1];
  __shared__ float redv[4], redl[4];
  __shared__ int redi[4], redr[4];
  __shared__ int s_gsel, s_bstar;
  __shared__ uint32_t s_c2;
  __shared__ float sh_kth, sh_cut, sh_mpthr, sh_m, sh_L, sh_safe_t, sh_mx, sh_Sx, sh_tlp;

  for (int i = tid; i < NBINS; i += K4B) h[i] = 0u;
  if (tid == 0) {
    int o = 0;
    for (int c = 0; c < NS; c++) {
      soff[c] = o;
      int cc = (int)pcnt[row * NS + c];
      if (cc > SEG) cc = SEG;
      o += cc;
    }
    soff[NS] = o;
    s_gsel = 0; s_c2 = 0u;
  }
  __syncthreads();
  const int total = soff[NS];
  for (int idx = tid; idx < NS * SEG; idx += K4B) {
    int c = idx / SEG, i = idx - c * SEG;
    int cc = soff[c + 1] - soff[c];
    if (i < cc) cd[soff[c] + i] = candG[((size_t)row * NS + c) * SEG + i];
  }
  __syncthreads();

  // ---- candidate histogram (same 8192-bin ord space) ----
  for (int e = tid; e < total; e += K4B) {
    uint32_t bin = (~(uint32_t)(cd[e] >> 32)) >> 19;
    atomicAdd(&h[bin], 1u);
  }
  __syncthreads();

  // ---- suffix scan over 256 groups of 32 bins -> global bstar ----
  {
    uint32_t g = 0;
    #pragma unroll
    for (int b = 0; b < 32; b++) g += h[tid * 32 + b];
    sfx[tid] = g;
    if (tid == 0) sfx[K4B] = 0;
    __syncthreads();
    for (int off = 1; off < K4B; off <<= 1) {
      uint32_t v = (tid + off < K4B) ? sfx[tid + off] : 0u;
      __syncthreads();
      sfx[tid] += v;
      __syncthreads();
    }
    uint32_t gs = sfx[tid], gn = sfx[tid + 1];
    if (gs >= CAND_MIN && gn < CAND_MIN) s_gsel = tid;
    __syncthreads();
  }
  if (tid == 0) {
    int gsl = s_gsel;
    uint32_t cum = sfx[gsl + 1];
    int bsel = gsl * 32;
    for (int b = gsl * 32 + 31; b >= gsl * 32; b--) {
      cum += h[b];
      if (cum >= CAND_MIN) { bsel = b; break; }
    }
    s_bstar = bsel;
  }
  __syncthreads();

  // ---- compact survivors (bin >= global bstar; cap CANDC >= total, no loss) ----
  const int bst = s_bstar;
  for (int e = tid; e < total; e += K4B) {
    uint64_t c = cd[e];
    if ((int)((~(uint32_t)(c >> 32)) >> 19) >= bst) {
      uint32_t slot = atomicAdd(&s_c2, 1u);
      cd2[slot] = c;
    }
  }
  __syncthreads();
  const int cnt2 = (int)s_c2;
  int N2 = 256; while (N2 < cnt2) N2 <<= 1;
  for (int e = cnt2 + tid; e < N2; e += K4B) cd2[e] = ~0ull;
  __syncthreads();

  // ---- bitonic sort cd2[0..N2) ascending (value desc, idx asc) ----
  for (int ks = 2; ks <= N2; ks <<= 1) {
    for (int j = ks >> 1; j; j >>= 1) {
      for (int e = tid; e < N2; e += K4B) {
        int p = e ^ j;
        if (p > e) {
          uint64_t a = cd2[e], b = cd2[p];
          bool up = ((e & ks) == 0);
          if ((a > b) == up) { cd2[e] = b; cd2[p] = a; }
        }
      }
      __syncthreads();
    }
  }

  if (tid == 0) {
    float t = temp_[row];
    float safe_t = (t < EPSV) ? 1.0f : t;
    float m = pmax[row * NS + 0];
    for (int c = 1; c < NS; c++) m = fmaxf(m, pmax[row * NS + c]);
    float m_x = m / safe_t;
    float S = 0, Sx = 0;
    for (int c = 0; c < NS; c++) {
      float mc = pmax[row * NS + c];
      S  += pS[row * NS + c]  * expf(mc - m);
      Sx += pSx[row * NS + c] * expf(mc / safe_t - m_x);
    }
    float L = logf(S);
    int i64mode = (B > 1 && topk_[1] == 0) ? 1 : 0;
    int kraw = i64mode ? topk_[2 * row] : topk_[row];
    int k = kraw < 1 ? 1 : (kraw > V ? V : kraw);
    int keff = k < cnt2 ? k : cnt2;
    float mpthr = minp_[row] * (1.0f / Sx);
    float topp = topp_[row];
    int np = 0;
    while (np < keff) {
      float xl = fromOrd(~(uint32_t)(cd2[np] >> 32)) / safe_t;
      float p = expf(xl - m_x) / Sx;
      if (p < mpthr) break;
      np++;
    }
    float kth_x = NEGV;
    if (np == k) kth_x = fromOrd(~(uint32_t)(cd2[k - 1] >> 32)) / safe_t;
    int kk = np;
    float S2 = 0.f;
    for (int i = 0; i < kk; i++)
      S2 += expf(fromOrd(~(uint32_t)(cd2[i] >> 32)) / safe_t - m_x);
    float cum = 0.f; int nkeep = 0;
    for (int i = 0; i < kk; i++) {
      float xl = fromOrd(~(uint32_t)(cd2[i] >> 32)) / safe_t;
      float sp = expf(xl - m_x) / S2;
      cum += sp;
      if (cum - sp < topp) nkeep++;
    }
    float cutoff_x = NEGV;
    if (!(cum < topp)) {
      if (nkeep < 1) nkeep = 1;
      cutoff_x = fromOrd(~(uint32_t)(cd2[nkeep - 1] >> 32)) / safe_t;
    }
    sh_kth = kth_x; sh_cut = cutoff_x; sh_mpthr = mpthr; sh_m = m; sh_L = L;
    sh_safe_t = safe_t; sh_mx = m_x; sh_Sx = Sx;
  }
  __syncthreads();

  // ---- gumbel argmax over kept survivors (scattered noise reads) ----
  float bestv = -INFINITY, bestl = 0.f; int besti = 0x7fffffff;
  for (int e = tid; e < cnt2; e += K4B) {
    uint64_t c = cd2[e];
    float l = fromOrd(~(uint32_t)(c >> 32));
    int idx = (int)(uint32_t)(c & 0xffffffffu);
    float x = l / sh_safe_t;
    float p = expf(x - sh_mx) / sh_Sx;
    if (p >= sh_mpthr && x >= sh_kth && x >= sh_cut) {
      float u = noise_[(size_t)row * V + idx];
      float v = x + (-logf(-logf(u)));
      if (v > bestv || (v == bestv && idx < besti)) { bestv = v; besti = idx; bestl = l; }
    }
  }
  #pragma unroll
  for (int o = 32; o; o >>= 1) {
    float ov = __shfl_down(bestv, o); int oi = __shfl_down(besti, o); float ol = __shfl_down(bestl, o);
    if (ov > bestv || (ov == bestv && oi < besti)) { bestv = ov; besti = oi; bestl = ol; }
  }
  if (lane == 0) { redv[wv] = bestv; redi[wv] = besti; redl[wv] = bestl; }
  __syncthreads();
  if (tid == 0) {
    float bv = redv[0]; int bi = redi[0]; float bl = redl[0];
    for (int w = 1; w < 4; w++) {
      if (redv[w] > bv || (redv[w] == bv && redi[w] < bi)) { bv = redv[w]; bi = redi[w]; bl = redl[w]; }
    }
    float t = temp_[row];
    int sampled; float ls;
    if (t < EPSV) {
      uint64_t c0 = cd2[0];
      sampled = (int)(uint32_t)(c0 & 0xffffffffu);
      ls = fromOrd(~(uint32_t)(c0 >> 32));
    } else { sampled = bi; ls = bl; }
    float token_lp = (ls - sh_m) - sh_L;
    sh_tlp = token_lp;
    float* out_idx = out + B;
    float* out_lp = out + B + (size_t)B * (1 + nlp);
    size_t rb = (size_t)row * (1 + nlp);
    out[row] = (float)sampled;
    out_idx[rb] = (float)sampled;
    out_lp[rb] = token_lp;
    for (int j = 0; j < nlp; j++) {
      uint64_t c = cd2[j];
      out_idx[rb + 1 + j] = (float)(int)(uint32_t)(c & 0xffffffffu);
      out_lp[rb + 1 + j] = (fromOrd(~(uint32_t)(c >> 32)) - sh_m) - sh_L;
    }
  }
  __syncthreads();

  // ---- rank over survivors (all elements >= token are in global top-128 ⊆ survivors) ----
  int rc = 0;
  for (int e = tid; e < cnt2; e += K4B) {
    float l = fromOrd(~(uint32_t)(cd2[e] >> 32));
    float f = (l - sh_m) - sh_L;
    rc += (f >= sh_tlp) ? 1 : 0;
  }
  #pragma unroll
  for (int o = 32; o; o >>= 1) rc += __shfl_down(rc, o);
  if (lane == 0) redr[wv] = rc;
  __syncthreads();
  if (tid == 0) {
    int r = 0;
    for (int w = 0; w < 4; w++) r += redr[w];
    out[B + 2 * (size_t)B * (1 + nlp) + row] = (float)r;
  }
}

// ================= fallback: proven monolithic kernel (R2, passed) =================
#define FB_BLOCK 1024
#define FB_CAP 2048
#define FB_NW 16

struct FBSM {
  uint32_t hist[NBINS];
  uint64_t cand[FB_CAP];
  float redf[FB_NW];
  int   redi[FB_NW];
  int cnt; int bstar;
  float m, S, Sx;
  float kth_x, cutoff_x, mpthr;
  float L, token_lp;
  int greedy;
};

__device__ __forceinline__ float fbCandVal(const uint64_t* cand, int i) {
  return fromOrd(~(uint32_t)(cand[i] >> 32));
}

__global__ void __launch_bounds__(FB_BLOCK)
sampler_fallback(const float* __restrict__ logits, const float* __restrict__ temp_,
                 const float* __restrict__ minp_, const float* __restrict__ topp_,
                 const int* __restrict__ topk_, const float* __restrict__ noise_,
                 float* __restrict__ out, int B, int V, int nlp)
{
  __shared__ FBSM sm;
  const int row = blockIdx.x, tid = threadIdx.x, lane = tid & 63, wv = tid >> 6;
  const float* lrow = logits + (size_t)row * V;
  const float* nrow = noise_ + (size_t)row * V;
  const int V4 = V >> 2, Vt = V4 << 2;
  const float4* l4 = (const float4*)lrow;
  const float4* n4 = (const float4*)nrow;
  for (int i = tid; i < NBINS; i += FB_BLOCK) sm.hist[i] = 0u;
  if (tid == 0) sm.cnt = 0;
  __syncthreads();
  float lmax = -INFINITY;
  for (int i = tid; i < V4; i += FB_BLOCK) {
    float4 v = l4[i]; float a[4] = {v.x, v.y, v.z, v.w};
    #pragma unroll
    for (int c = 0; c < 4; c++) { lmax = fmaxf(lmax, a[c]); atomicAdd(&sm.hist[toOrd(a[c]) >> 19], 1u); }
  }
  for (int i = Vt + tid; i < V; i += FB_BLOCK) {
    float a = lrow[i]; lmax = fmaxf(lmax, a); atomicAdd(&sm.hist[toOrd(a) >> 19], 1u);
  }
  #pragma unroll
  for (int o = 32; o; o >>= 1) lmax = fmaxf(lmax, __shfl_down(lmax, o));
  if (lane == 0) sm.redf[wv] = lmax;
  __syncthreads();
  if (tid == 0) {
    float mm = sm.redf[0];
    for (int w = 1; w < FB_NW; w++) mm = fmaxf(mm, sm.redf[w]);
    sm.m = mm;
    uint32_t cum = 0; int b = NBINS - 1;
    for (; b > 0; b--) { cum += sm.hist[b]; if (cum >= CAND_MIN) break; }
    sm.bstar = b;
  }
  __syncthreads();
  const float m = sm.m;
  const int bstar = sm.bstar;
  const float t = temp_[row];
  const float safe_t = (t < EPSV) ? 1.0f : t;
  const float m_x = m / safe_t;
  float S = 0.f, Sx = 0.f;
  for (int i = tid; i < V4; i += FB_BLOCK) {
    float4 v = l4[i]; float a[4] = {v.x, v.y, v.z, v.w};
    #pragma unroll
    for (int c = 0; c < 4; c++) {
      S += expf(a[c] - m);
      float x = a[c] / safe_t; Sx += expf(x - m_x);
      uint32_t o = toOrd(a[c]);
      if ((int)(o >> 19) >= bstar) {
        int slot = atomicAdd(&sm.cnt, 1);
        if (slot < FB_CAP) sm.cand[slot] = ((uint64_t)(~o) << 32) | (uint32_t)(i * 4 + c);
      }
    }
  }
  for (int i = Vt + tid; i < V; i += FB_BLOCK) {
    float a = lrow[i];
    S += expf(a - m);
    float x = a / safe_t; Sx += expf(x - m_x);
    uint32_t o = toOrd(a);
    if ((int)(o >> 19) >= bstar) {
      int slot = atomicAdd(&sm.cnt, 1);
      if (slot < FB_CAP) sm.cand[slot] = ((uint64_t)(~o) << 32) | (uint32_t)i;
    }
  }
  #pragma unroll
  for (int o = 32; o; o >>= 1) { S += __shfl_down(S, o); Sx += __shfl_down(Sx, o); }
  if (lane == 0) sm.redf[wv] = S;
  __syncthreads();
  if (tid == 0) { float s = 0; for (int w = 0; w < FB_NW; w++) s += sm.redf[w]; sm.S = s; }
  __syncthreads();
  if (lane == 0) sm.redf[wv] = Sx;
  __syncthreads();
  if (tid == 0) { float s = 0; for (int w = 0; w < FB_NW; w++) s += sm.redf[w]; sm.Sx = s; }
  __syncthreads();
  const int count = min(sm.cnt, FB_CAP);
  for (int i = count + tid; i < FB_CAP; i += FB_BLOCK) sm.cand[i] = ~0ull;
  __syncthreads();
  for (int ks = 2; ks <= FB_CAP; ks <<= 1) {
    for (int j = ks >> 1; j > 0; j >>= 1) {
      for (int e = tid; e < FB_CAP; e += FB_BLOCK) {
        int p = e ^ j;
        if (p > e) {
          uint64_t a = sm.cand[e], b2 = sm.cand[p];
          bool up = ((e & ks) == 0);
          if ((a > b2) == up) { sm.cand[e] = b2; sm.cand[p] = a; }
        }
      }
      __syncthreads();
    }
  }
  if (tid == 0) {
    const float Sx_ = sm.Sx;
    const float L = logf(sm.S);
    sm.L = L;
    int i64mode = (B > 1 && topk_[1] == 0) ? 1 : 0;
    int kraw = i64mode ? topk_[2 * row] : topk_[row];
    int k = kraw < 1 ? 1 : (kraw > V ? V : kraw);
    int keff = k < count ? k : count;
    float mpthr = minp_[row] * (1.0f / Sx_);
    sm.mpthr = mpthr;
    float topp = topp_[row];
    int np = 0;
    while (np < keff) {
      float xl = fbCandVal(sm.cand, np) / safe_t;
      float p = expf(xl - m_x) / Sx_;
      if (p < mpthr) break;
      np++;
    }
    float kth_x = NEGV;
    if (np == k) kth_x = fbCandVal(sm.cand, k - 1) / safe_t;
    int kk = np;
    float S2 = 0.f;
    for (int i = 0; i < kk; i++) S2 += expf(fbCandVal(sm.cand, i) / safe_t - m_x);
    float cum = 0.f; int nkeep = 0;
    for (int i = 0; i < kk; i++) {
      float xl = fbCandVal(sm.cand, i) / safe_t;
      float sp = expf(xl - m_x) / S2;
      cum += sp;
      if (cum - sp < topp) nkeep++;
    }
    float cutoff_x = NEGV;
    if (!(cum < topp)) { if (nkeep < 1) nkeep = 1; cutoff_x = fbCandVal(sm.cand, nkeep - 1) / safe_t; }
    sm.kth_x = kth_x; sm.cutoff_x = cutoff_x;
    sm.greedy = (int)(uint32_t)(sm.cand[0] & 0xffffffffu);
  }
  __syncthreads();
  const float kth_x = sm.kth_x, cutoff_x = sm.cutoff_x, mpthr = sm.mpthr, SxR = sm.Sx;
  float bestv = -INFINITY; int besti = 0;
  for (int i = tid; i < V4; i += FB_BLOCK) {
    float4 lv = l4[i]; float4 uv = n4[i];
    float la[4] = {lv.x, lv.y, lv.z, lv.w};
    float ua[4] = {uv.x, uv.y, uv.z, uv.w};
    #pragma unroll
    for (int c = 0; c < 4; c++) {
      float x = la[c] / safe_t;
      float p = expf(x - m_x) / SxR;
      float val = NEGV;
      if (p >= mpthr && x >= kth_x && x >= cutoff_x) val = x + (-logf(-logf(ua[c])));
      if (val > bestv) { bestv = val; besti = i * 4 + c; }
    }
  }
  for (int i = Vt + tid; i < V; i += FB_BLOCK) {
    float x = lrow[i] / safe_t;
    float p = expf(x - m_x) / SxR;
    float val = NEGV;
    if (p >= mpthr && x >= kth_x && x >= cutoff_x) val = x + (-logf(-logf(nrow[i])));
    if (val > bestv) { bestv = val; besti = i; }
  }
  #pragma unroll
  for (int o = 32; o; o >>= 1) {
    float ov = __shfl_down(bestv, o); int oi = __shfl_down(besti, o);
    if (ov > bestv || (ov == bestv && oi < besti)) { bestv = ov; besti = oi; }
  }
  if (lane == 0) { sm.redf[wv] = bestv; sm.redi[wv] = besti; }
  __syncthreads();
  if (tid == 0) {
    float bv = sm.redf[0]; int bi = sm.redi[0];
    for (int w = 1; w < FB_NW; w++) {
      if (sm.redf[w] > bv || (sm.redf[w] == bv && sm.redi[w] < bi)) { bv = sm.redf[w]; bi = sm.redi[w]; }
    }
    int sampled = (t < EPSV) ? sm.greedy : bi;
    float ls = lrow[sampled];
    float token_lp = (ls - m) - sm.L;
    sm.token_lp = token_lp;
    float* out_idx = out + B;
    float* out_lp = out + B + (size_t)B * (1 + nlp);
    size_t rb = (size_t)row * (1 + nlp);
    out[row] = (float)sampled;
    out_idx[rb] = (float)sampled;
    out_lp[rb] = token_lp;
    for (int j = 0; j < nlp; j++) {
      uint64_t cdv = sm.cand[j];
      out_idx[rb + 1 + j] = (float)(int)(uint32_t)(cdv & 0xffffffffu);
      out_lp[rb + 1 + j] = (fromOrd(~(uint32_t)(cdv >> 32)) - m) - sm.L;
    }
  }
  __syncthreads();
  const float Lc = sm.L, tlp = sm.token_lp;
  int cnt = 0;
  for (int i = tid; i < V4; i += FB_BLOCK) {
    float4 v = l4[i]; float a[4] = {v.x, v.y, v.z, v.w};
    #pragma unroll
    for (int c = 0; c < 4; c++) { float lp = (a[c] - m) - Lc; cnt += (lp >= tlp) ? 1 : 0; }
  }
  for (int i = Vt + tid; i < V; i += FB_BLOCK) {
    float lp = (lrow[i] - m) - Lc; cnt += (lp >= tlp) ? 1 : 0;
  }
  #pragma unroll
  for (int o = 32; o; o >>= 1) cnt += __shfl_down(cnt, o);
  if (lane == 0) sm.redi[wv] = cnt;
  __syncthreads();
  if (tid == 0) {
    int r = 0;
    for (int w = 0; w < FB_NW; w++) r += sm.redi[w];
    out[B + 2 * (size_t)B * (1 + nlp) + row] = (float)r;
  }
}

extern "C" void kernel_launch(void* const* d_in, const int* in_sizes, int n_in,
                              void* d_out, int out_size, void* d_ws, size_t ws_size,
                              hipStream_t stream) {
  const float* logits = (const float*)d_in[0];
  const float* temp   = (const float*)d_in[1];
  const float* minp   = (const float*)d_in[2];
  const float* topp   = (const float*)d_in[3];
  const int*   topk   = (const int*)d_in[4];
  const float* noise  = (const float*)d_in[5];
  int B = in_sizes[1];
  int V = in_sizes[0] / B;
  int nlp = (out_size / B - 4) / 2;
  if (nlp < 0) nlp = 0;

  uint8_t* ws = (uint8_t*)d_ws;
  size_t off = 0;
  uint32_t* pcnt = (uint32_t*)(ws + off); off += (size_t)B * NS * 4;
  float* pmax = (float*)(ws + off); off += (size_t)B * NS * 4;
  float* pS   = (float*)(ws + off); off += (size_t)B * NS * 4;
  float* pSx  = (float*)(ws + off); off += (size_t)B * NS * 4;
  off = (off + 7) & ~(size_t)7;
  uint64_t* cand = (uint64_t*)(ws + off); off += (size_t)B * NS * SEG * 8;

  if (ws_size < off) {
    hipLaunchKernelGGL(sampler_fallback, dim3(B), dim3(FB_BLOCK), 0, stream,
                       logits, temp, minp, topp, topk, noise, (float*)d_out, B, V, nlp);
    return;
  }

  hipLaunchKernelGGL(k3_fused, dim3(NS, B), dim3(K3B), 0, stream,
                     logits, temp, pmax, pS, pSx, pcnt, cand, V);
  hipLaunchKernelGGL(k4_final, dim3(B), dim3(K4B), 0, stream,
                     temp, minp, topp, topk, noise, pmax, pS, pSx, pcnt, cand,
                     (float*)d_out, B, V, nlp);
}

// Round 10
// 184.286 us; speedup vs baseline: 3.7887x; 1.2070x over previous
//
#include <hip/hip_runtime.h>
#include <stdint.h>
#include <math.h>

#define NS 8
#define K3B 512
#define K4B 256
#define NBINS 8192
#define SEG 320
#define CANDC 4096
#define CAND_MIN 128
#define NEGV -1e30f
#define EPSV 1e-5f

__device__ __forceinline__ uint32_t toOrd(float f) {
  uint32_t u = __float_as_uint(f);
  return (u & 0x80000000u) ? ~u : (u | 0x80000000u);
}
__device__ __forceinline__ float fromOrd(uint32_t o) {
  uint32_t u = (o & 0x80000000u) ? (o & 0x7fffffffu) : ~o;
  return __uint_as_float(u);
}

// ---- K3: per-(row,chunk): hist+max -> bstar -> S + private candidate collect ----
// (Sx eliminated: min_p test reduces to expf(x - m_x) >= min_p since top_prob = 1/Sx.)
__global__ void __launch_bounds__(K3B)
k3_fused(const float* __restrict__ logits,
         float* __restrict__ pmax, float* __restrict__ pS,
         uint32_t* __restrict__ pcnt, uint64_t* __restrict__ cand, int V)
{
  const int chunk = blockIdx.x, row = blockIdx.y;
  const int tid = threadIdx.x, lane = tid & 63, wv = tid >> 6;
  __shared__ uint32_t h[NBINS];
  __shared__ uint32_t sfx[K3B];
  __shared__ uint32_t wtot[8];
  __shared__ float redf[8];
  __shared__ int s_gsel, s_bstar;
  __shared__ float s_m;
  __shared__ uint32_t s_loc;
  __shared__ uint64_t stage[SEG];

  for (int i = tid; i < NBINS; i += K3B) h[i] = 0u;
  if (tid == 0) { s_loc = 0u; s_gsel = 0; }
  __syncthreads();

  const int clen = ((V + NS - 1) / NS + 3) & ~3;
  const int start = chunk * clen;
  int valid = V - start;
  if (valid < 0) valid = 0;
  if (valid > clen) valid = clen;
  const int nf4 = valid >> 2;
  const float* crow = logits + (size_t)row * V + start;
  const float4* p4 = (const float4*)crow;

  // ---- pass A: chunk max + LDS histogram ----
  float lmax = -INFINITY;
  for (int i = tid; i < nf4; i += K3B) {
    float4 v = p4[i];
    float a[4] = {v.x, v.y, v.z, v.w};
    #pragma unroll
    for (int c = 0; c < 4; c++) {
      lmax = fmaxf(lmax, a[c]);
      atomicAdd(&h[toOrd(a[c]) >> 19], 1u);
    }
  }
  for (int i = (nf4 << 2) + tid; i < valid; i += K3B) {
    float a = crow[i];
    lmax = fmaxf(lmax, a);
    atomicAdd(&h[toOrd(a) >> 19], 1u);
  }
  #pragma unroll
  for (int o = 32; o; o >>= 1) lmax = fmaxf(lmax, __shfl_down(lmax, o));
  if (lane == 0) redf[wv] = lmax;
  __syncthreads();

  // ---- suffix sums via wave shuffles (2 barriers instead of 18) ----
  {
    uint32_t g = 0;
    #pragma unroll
    for (int b = 0; b < 16; b++) g += h[tid * 16 + b];
    uint32_t x = g;
    #pragma unroll
    for (int off = 1; off < 64; off <<= 1) {
      uint32_t v = __shfl_down(x, off);
      if (lane + off < 64) x += v;
    }
    if (lane == 0) wtot[wv] = x;   // wave total = suffix at lane 0
    __syncthreads();
    uint32_t tail = 0;
    for (int w = wv + 1; w < 8; w++) tail += wtot[w];
    uint32_t gs = x + tail;        // inclusive suffix sum from group tid
    uint32_t gn = gs - g;          // suffix after group tid
    sfx[tid] = gs;
    if (gs >= CAND_MIN && gn < CAND_MIN) s_gsel = tid;
    __syncthreads();
  }
  if (tid == 0) {
    int gsl = s_gsel;
    uint32_t gg = 0;
    for (int b = 0; b < 16; b++) gg += h[gsl * 16 + b];
    uint32_t cum = sfx[gsl] - gg;  // suffix after group gsl
    int bsel = gsl * 16;
    for (int b = gsl * 16 + 15; b >= gsl * 16; b--) {
      cum += h[b];
      if (cum >= CAND_MIN) { bsel = b; break; }
    }
    s_bstar = bsel;
    float mm = redf[0];
    for (int w = 1; w < 8; w++) mm = fmaxf(mm, redf[w]);
    s_m = mm;
    pmax[row * NS + chunk] = mm;
  }
  __syncthreads();

  const float m_c = s_m;
  const int bst = s_bstar;

  // ---- pass B (L2 re-read): S sum + LDS-private candidate collect ----
  float S = 0.f;
  for (int i = tid; i < nf4; i += K3B) {
    float4 v = p4[i];
    float a[4] = {v.x, v.y, v.z, v.w};
    #pragma unroll
    for (int c = 0; c < 4; c++) {
      S += expf(a[c] - m_c);
      uint32_t o = toOrd(a[c]);
      if ((int)(o >> 19) >= bst) {
        uint32_t slot = atomicAdd(&s_loc, 1u);
        if (slot < SEG)
          stage[slot] = ((uint64_t)(~o) << 32) | (uint32_t)(start + i * 4 + c);
      }
    }
  }
  for (int i = (nf4 << 2) + tid; i < valid; i += K3B) {
    float a = crow[i];
    S += expf(a - m_c);
    uint32_t o = toOrd(a);
    if ((int)(o >> 19) >= bst) {
      uint32_t slot = atomicAdd(&s_loc, 1u);
      if (slot < SEG)
        stage[slot] = ((uint64_t)(~o) << 32) | (uint32_t)(start + i);
    }
  }
  #pragma unroll
  for (int o = 32; o; o >>= 1) S += __shfl_down(S, o);
  if (lane == 0) redf[wv] = S;
  __syncthreads();
  if (tid == 0) {
    float s = 0;
    for (int w = 0; w < 8; w++) s += redf[w];
    pS[row * NS + chunk] = s;
  }
  // flush private segment (plain stores, no global atomics)
  int lc = (int)s_loc; if (lc > SEG) lc = SEG;
  for (int i = tid; i < lc; i += K3B)
    cand[((size_t)row * NS + chunk) * SEG + i] = stage[i];
  if (tid == 0) pcnt[row * NS + chunk] = (uint32_t)lc;
}

// ---- K4: gather, prune to global top-~128, small sort, parallel-precomputed cutoffs ----
union K4U {
  uint64_t cd[CANDC];
  struct { float xl[CANDC]; } px;   // overlaid after cd is dead
};

__global__ void __launch_bounds__(K4B)
k4_final(const float* __restrict__ temp_, const float* __restrict__ minp_,
         const float* __restrict__ topp_, const int* __restrict__ topk_,
         const float* __restrict__ noise_,
         const float* __restrict__ pmax, const float* __restrict__ pS,
         const uint32_t* __restrict__ pcnt,
         const uint64_t* __restrict__ candG, float* __restrict__ out,
         int B, int V, int nlp)
{
  const int row = blockIdx.x, tid = threadIdx.x, lane = tid & 63, wv = tid >> 6;
  __shared__ K4U u;
  __shared__ float exA[CANDC];
  __shared__ uint64_t cd2[CANDC];
  __shared__ uint32_t h[NBINS];
  __shared__ uint32_t sfx[K4B + 1];
  __shared__ int soff[NS + 1];
  __shared__ float redv[4], redl[4];
  __shared__ int redi[4], redr[4];
  __shared__ int s_gsel, s_bstar;
  __shared__ uint32_t s_c2;
  __shared__ float sh_kth, sh_cut, sh_mpthr, sh_m, sh_L, sh_safe_t, sh_mx, sh_tlp;

  for (int i = tid; i < NBINS; i += K4B) h[i] = 0u;
  if (tid == 0) {
    int o = 0;
    for (int c = 0; c < NS; c++) {
      soff[c] = o;
      int cc = (int)pcnt[row * NS + c];
      if (cc > SEG) cc = SEG;
      o += cc;
    }
    soff[NS] = o;
    s_gsel = 0; s_c2 = 0u;
  }
  __syncthreads();
  const int total = soff[NS];
  for (int idx = tid; idx < NS * SEG; idx += K4B) {
    int c = idx / SEG, i = idx - c * SEG;
    int cc = soff[c + 1] - soff[c];
    if (i < cc) u.cd[soff[c] + i] = candG[((size_t)row * NS + c) * SEG + i];
  }
  __syncthreads();

  // ---- candidate histogram over the 8192-bin ord space ----
  for (int e = tid; e < total; e += K4B) {
    uint32_t bin = (~(uint32_t)(u.cd[e] >> 32)) >> 19;
    atomicAdd(&h[bin], 1u);
  }
  __syncthreads();

  // ---- suffix scan (256 groups of 32 bins) -> global bstar ----
  {
    uint32_t g = 0;
    #pragma unroll
    for (int b = 0; b < 32; b++) g += h[tid * 32 + b];
    sfx[tid] = g;
    if (tid == 0) sfx[K4B] = 0;
    __syncthreads();
    for (int off = 1; off < K4B; off <<= 1) {
      uint32_t v = (tid + off < K4B) ? sfx[tid + off] : 0u;
      __syncthreads();
      sfx[tid] += v;
      __syncthreads();
    }
    uint32_t gs = sfx[tid], gn = sfx[tid + 1];
    if (gs >= CAND_MIN && gn < CAND_MIN) s_gsel = tid;
    __syncthreads();
  }
  if (tid == 0) {
    int gsl = s_gsel;
    uint32_t cum = sfx[gsl + 1];
    int bsel = gsl * 32;
    for (int b = gsl * 32 + 31; b >= gsl * 32; b--) {
      cum += h[b];
      if (cum >= CAND_MIN) { bsel = b; break; }
    }
    s_bstar = bsel;
  }
  __syncthreads();

  // ---- compact survivors ----
  const int bst = s_bstar;
  for (int e = tid; e < total; e += K4B) {
    uint64_t c = u.cd[e];
    if ((int)((~(uint32_t)(c >> 32)) >> 19) >= bst) {
      uint32_t slot = atomicAdd(&s_c2, 1u);
      cd2[slot] = c;
    }
  }
  __syncthreads();
  const int cnt2 = (int)s_c2;
  int N2 = 256; while (N2 < cnt2) N2 <<= 1;
  for (int e = cnt2 + tid; e < N2; e += K4B) cd2[e] = ~0ull;
  __syncthreads();

  // ---- bitonic sort cd2[0..N2) ascending (value desc, idx asc) ----
  for (int ks = 2; ks <= N2; ks <<= 1) {
    for (int j = ks >> 1; j; j >>= 1) {
      for (int e = tid; e < N2; e += K4B) {
        int p = e ^ j;
        if (p > e) {
          uint64_t a = cd2[e], b = cd2[p];
          bool up = ((e & ks) == 0);
          if ((a > b) == up) { cd2[e] = b; cd2[p] = a; }
        }
      }
      __syncthreads();
    }
  }

  // ---- phase 1 (tid0): combine partials, broadcast scalars ----
  int k_ = 0, keff_ = 0; float topp_v = 0.f;
  if (tid == 0) {
    float t = temp_[row];
    float safe_t = (t < EPSV) ? 1.0f : t;
    float m = pmax[row * NS + 0];
    for (int c = 1; c < NS; c++) m = fmaxf(m, pmax[row * NS + c]);
    float S = 0;
    for (int c = 0; c < NS; c++) S += pS[row * NS + c] * expf(pmax[row * NS + c] - m);
    float L = logf(S);
    int i64mode = (B > 1 && topk_[1] == 0) ? 1 : 0;
    int kraw = i64mode ? topk_[2 * row] : topk_[row];
    int k = kraw < 1 ? 1 : (kraw > V ? V : kraw);
    k_ = k; keff_ = k < cnt2 ? k : cnt2;
    topp_v = topp_[row];
    sh_m = m; sh_L = L; sh_safe_t = safe_t; sh_mx = m / safe_t;
    sh_mpthr = minp_[row];   // Sx cancels: p >= minp*top_prob  <=>  expf(x-m_x) >= minp
  }
  __syncthreads();

  // ---- parallel precompute xl/ex for all survivors (kills serial expf chains) ----
  {
    const float st = sh_safe_t, mx = sh_mx;
    for (int e = tid; e < cnt2; e += K4B) {
      float xl = fromOrd(~(uint32_t)(cd2[e] >> 32)) / st;
      u.px.xl[e] = xl;
      exA[e] = expf(xl - mx);
    }
  }
  __syncthreads();

  // ---- phase 2 (tid0): cutoffs via LDS-cached values, sequential add order preserved ----
  if (tid == 0) {
    const float mpthr = sh_mpthr;
    int np = 0;
    while (np < keff_ && exA[np] >= mpthr) np++;
    float kth_x = NEGV;
    if (np == k_) kth_x = u.px.xl[k_ - 1];
    int kk = np;
    float S2 = 0.f;
    for (int i = 0; i < kk; i++) S2 += exA[i];
    float cum = 0.f; int nkeep = 0;
    for (int i = 0; i < kk; i++) {
      float sp = exA[i] / S2;
      cum += sp;
      if (cum - sp < topp_v) nkeep++;
    }
    float cutoff_x = NEGV;
    if (!(cum < topp_v)) {
      if (nkeep < 1) nkeep = 1;
      cutoff_x = u.px.xl[nkeep - 1];
    }
    sh_kth = kth_x; sh_cut = cutoff_x;
  }
  __syncthreads();

  // ---- gumbel argmax over kept survivors (scattered noise reads) ----
  const float kth = sh_kth, cut = sh_cut, mpthr = sh_mpthr;
  float bestv = -INFINITY, bestl = 0.f; int besti = 0x7fffffff;
  for (int e = tid; e < cnt2; e += K4B) {
    float xl = u.px.xl[e];
    if (exA[e] >= mpthr && xl >= kth && xl >= cut) {
      uint64_t c = cd2[e];
      int idx = (int)(uint32_t)(c & 0xffffffffu);
      float un = noise_[(size_t)row * V + idx];
      float v = xl + (-logf(-logf(un)));
      if (v > bestv || (v == bestv && idx < besti)) {
        bestv = v; besti = idx; bestl = fromOrd(~(uint32_t)(c >> 32));
      }
    }
  }
  #pragma unroll
  for (int o = 32; o; o >>= 1) {
    float ov = __shfl_down(bestv, o); int oi = __shfl_down(besti, o); float ol = __shfl_down(bestl, o);
    if (ov > bestv || (ov == bestv && oi < besti)) { bestv = ov; besti = oi; bestl = ol; }
  }
  if (lane == 0) { redv[wv] = bestv; redi[wv] = besti; redl[wv] = bestl; }
  __syncthreads();
  if (tid == 0) {
    float bv = redv[0]; int bi = redi[0]; float bl = redl[0];
    for (int w = 1; w < 4; w++) {
      if (redv[w] > bv || (redv[w] == bv && redi[w] < bi)) { bv = redv[w]; bi = redi[w]; bl = redl[w]; }
    }
    float t = temp_[row];
    int sampled; float ls;
    if (t < EPSV) {
      uint64_t c0 = cd2[0];
      sampled = (int)(uint32_t)(c0 & 0xffffffffu);
      ls = fromOrd(~(uint32_t)(c0 >> 32));
    } else { sampled = bi; ls = bl; }
    float token_lp = (ls - sh_m) - sh_L;
    sh_tlp = token_lp;
    float* out_idx = out + B;
    float* out_lp = out + B + (size_t)B * (1 + nlp);
    size_t rb = (size_t)row * (1 + nlp);
    out[row] = (float)sampled;
    out_idx[rb] = (float)sampled;
    out_lp[rb] = token_lp;
    for (int j = 0; j < nlp; j++) {
      uint64_t c = cd2[j];
      out_idx[rb + 1 + j] = (float)(int)(uint32_t)(c & 0xffffffffu);
      out_lp[rb + 1 + j] = (fromOrd(~(uint32_t)(c >> 32)) - sh_m) - sh_L;
    }
  }
  __syncthreads();

  // ---- rank over survivors (everything >= token is in global top-128 ⊆ survivors) ----
  int rc = 0;
  for (int e = tid; e < cnt2; e += K4B) {
    float l = fromOrd(~(uint32_t)(cd2[e] >> 32));
    float f = (l - sh_m) - sh_L;
    rc += (f >= sh_tlp) ? 1 : 0;
  }
  #pragma unroll
  for (int o = 32; o; o >>= 1) rc += __shfl_down(rc, o);
  if (lane == 0) redr[wv] = rc;
  __syncthreads();
  if (tid == 0) {
    int r = 0;
    for (int w = 0; w < 4; w++) r += redr[w];
    out[B + 2 * (size_t)B * (1 + nlp) + row] = (float)r;
  }
}

// ================= fallback: proven monolithic kernel (R2, passed) =================
#define FB_BLOCK 1024
#define FB_CAP 2048
#define FB_NW 16

struct FBSM {
  uint32_t hist[NBINS];
  uint64_t cand[FB_CAP];
  float redf[FB_NW];
  int   redi[FB_NW];
  int cnt; int bstar;
  float m, S, Sx;
  float kth_x, cutoff_x, mpthr;
  float L, token_lp;
  int greedy;
};

__device__ __forceinline__ float fbCandVal(const uint64_t* cand, int i) {
  return fromOrd(~(uint32_t)(cand[i] >> 32));
}

__global__ void __launch_bounds__(FB_BLOCK)
sampler_fallback(const float* __restrict__ logits, const float* __restrict__ temp_,
                 const float* __restrict__ minp_, const float* __restrict__ topp_,
                 const int* __restrict__ topk_, const float* __restrict__ noise_,
                 float* __restrict__ out, int B, int V, int nlp)
{
  __shared__ FBSM sm;
  const int row = blockIdx.x, tid = threadIdx.x, lane = tid & 63, wv = tid >> 6;
  const float* lrow = logits + (size_t)row * V;
  const float* nrow = noise_ + (size_t)row * V;
  const int V4 = V >> 2, Vt = V4 << 2;
  const float4* l4 = (const float4*)lrow;
  const float4* n4 = (const float4*)nrow;
  for (int i = tid; i < NBINS; i += FB_BLOCK) sm.hist[i] = 0u;
  if (tid == 0) sm.cnt = 0;
  __syncthreads();
  float lmax = -INFINITY;
  for (int i = tid; i < V4; i += FB_BLOCK) {
    float4 v = l4[i]; float a[4] = {v.x, v.y, v.z, v.w};
    #pragma unroll
    for (int c = 0; c < 4; c++) { lmax = fmaxf(lmax, a[c]); atomicAdd(&sm.hist[toOrd(a[c]) >> 19], 1u); }
  }
  for (int i = Vt + tid; i < V; i += FB_BLOCK) {
    float a = lrow[i]; lmax = fmaxf(lmax, a); atomicAdd(&sm.hist[toOrd(a) >> 19], 1u);
  }
  #pragma unroll
  for (int o = 32; o; o >>= 1) lmax = fmaxf(lmax, __shfl_down(lmax, o));
  if (lane == 0) sm.redf[wv] = lmax;
  __syncthreads();
  if (tid == 0) {
    float mm = sm.redf[0];
    for (int w = 1; w < FB_NW; w++) mm = fmaxf(mm, sm.redf[w]);
    sm.m = mm;
    uint32_t cum = 0; int b = NBINS - 1;
    for (; b > 0; b--) { cum += sm.hist[b]; if (cum >= CAND_MIN) break; }
    sm.bstar = b;
  }
  __syncthreads();
  const float m = sm.m;
  const int bstar = sm.bstar;
  const float t = temp_[row];
  const float safe_t = (t < EPSV) ? 1.0f : t;
  const float m_x = m / safe_t;
  float S = 0.f, Sx = 0.f;
  for (int i = tid; i < V4; i += FB_BLOCK) {
    float4 v = l4[i]; float a[4] = {v.x, v.y, v.z, v.w};
    #pragma unroll
    for (int c = 0; c < 4; c++) {
      S += expf(a[c] - m);
      float x = a[c] / safe_t; Sx += expf(x - m_x);
      uint32_t o = toOrd(a[c]);
      if ((int)(o >> 19) >= bstar) {
        int slot = atomicAdd(&sm.cnt, 1);
        if (slot < FB_CAP) sm.cand[slot] = ((uint64_t)(~o) << 32) | (uint32_t)(i * 4 + c);
      }
    }
  }
  for (int i = Vt + tid; i < V; i += FB_BLOCK) {
    float a = lrow[i];
    S += expf(a - m);
    float x = a / safe_t; Sx += expf(x - m_x);
    uint32_t o = toOrd(a);
    if ((int)(o >> 19) >= bstar) {
      int slot = atomicAdd(&sm.cnt, 1);
      if (slot < FB_CAP) sm.cand[slot] = ((uint64_t)(~o) << 32) | (uint32_t)i;
    }
  }
  #pragma unroll
  for (int o = 32; o; o >>= 1) { S += __shfl_down(S, o); Sx += __shfl_down(Sx, o); }
  if (lane == 0) sm.redf[wv] = S;
  __syncthreads();
  if (tid == 0) { float s = 0; for (int w = 0; w < FB_NW; w++) s += sm.redf[w]; sm.S = s; }
  __syncthreads();
  if (lane == 0) sm.redf[wv] = Sx;
  __syncthreads();
  if (tid == 0) { float s = 0; for (int w = 0; w < FB_NW; w++) s += sm.redf[w]; sm.Sx = s; }
  __syncthreads();
  const int count = min(sm.cnt, FB_CAP);
  for (int i = count + tid; i < FB_CAP; i += FB_BLOCK) sm.cand[i] = ~0ull;
  __syncthreads();
  for (int ks = 2; ks <= FB_CAP; ks <<= 1) {
    for (int j = ks >> 1; j > 0; j >>= 1) {
      for (int e = tid; e < FB_CAP; e += FB_BLOCK) {
        int p = e ^ j;
        if (p > e) {
          uint64_t a = sm.cand[e], b2 = sm.cand[p];
          bool up = ((e & ks) == 0);
          if ((a > b2) == up) { sm.cand[e] = b2; sm.cand[p] = a; }
        }
      }
      __syncthreads();
    }
  }
  if (tid == 0) {
    const float Sx_ = sm.Sx;
    const float L = logf(sm.S);
    sm.L = L;
    int i64mode = (B > 1 && topk_[1] == 0) ? 1 : 0;
    int kraw = i64mode ? topk_[2 * row] : topk_[row];
    int k = kraw < 1 ? 1 : (kraw > V ? V : kraw);
    int keff = k < count ? k : count;
    float mpthr = minp_[row] * (1.0f / Sx_);
    sm.mpthr = mpthr;
    float topp = topp_[row];
    int np = 0;
    while (np < keff) {
      float xl = fbCandVal(sm.cand, np) / safe_t;
      float p = expf(xl - m_x) / Sx_;
      if (p < mpthr) break;
      np++;
    }
    float kth_x = NEGV;
    if (np == k) kth_x = fbCandVal(sm.cand, k - 1) / safe_t;
    int kk = np;
    float S2 = 0.f;
    for (int i = 0; i < kk; i++) S2 += expf(fbCandVal(sm.cand, i) / safe_t - m_x);
    float cum = 0.f; int nkeep = 0;
    for (int i = 0; i < kk; i++) {
      float xl = fbCandVal(sm.cand, i) / safe_t;
      float sp = expf(xl - m_x) / S2;
      cum += sp;
      if (cum - sp < topp) nkeep++;
    }
    float cutoff_x = NEGV;
    if (!(cum < topp)) { if (nkeep < 1) nkeep = 1; cutoff_x = fbCandVal(sm.cand, nkeep - 1) / safe_t; }
    sm.kth_x = kth_x; sm.cutoff_x = cutoff_x;
    sm.greedy = (int)(uint32_t)(sm.cand[0] & 0xffffffffu);
  }
  __syncthreads();
  const float kth_x = sm.kth_x, cutoff_x = sm.cutoff_x, mpthr = sm.mpthr, SxR = sm.Sx;
  float bestv = -INFINITY; int besti = 0;
  for (int i = tid; i < V4; i += FB_BLOCK) {
    float4 lv = l4[i]; float4 uv = n4[i];
    float la[4] = {lv.x, lv.y, lv.z, lv.w};
    float ua[4] = {uv.x, uv.y, uv.z, uv.w};
    #pragma unroll
    for (int c = 0; c < 4; c++) {
      float x = la[c] / safe_t;
      float p = expf(x - m_x) / SxR;
      float val = NEGV;
      if (p >= mpthr && x >= kth_x && x >= cutoff_x) val = x + (-logf(-logf(ua[c])));
      if (val > bestv) { bestv = val; besti = i * 4 + c; }
    }
  }
  for (int i = Vt + tid; i < V; i += FB_BLOCK) {
    float x = lrow[i] / safe_t;
    float p = expf(x - m_x) / SxR;
    float val = NEGV;
    if (p >= mpthr && x >= kth_x && x >= cutoff_x) val = x + (-logf(-logf(nrow[i])));
    if (val > bestv) { bestv = val; besti = i; }
  }
  #pragma unroll
  for (int o = 32; o; o >>= 1) {
    float ov = __shfl_down(bestv, o); int oi = __shfl_down(besti, o);
    if (ov > bestv || (ov == bestv && oi < besti)) { bestv = ov; besti = oi; }
  }
  if (lane == 0) { sm.redf[wv] = bestv; sm.redi[wv] = besti; }
  __syncthreads();
  if (tid == 0) {
    float bv = sm.redf[0]; int bi = sm.redi[0];
    for (int w = 1; w < FB_NW; w++) {
      if (sm.redf[w] > bv || (sm.redf[w] == bv && sm.redi[w] < bi)) { bv = sm.redf[w]; bi = sm.redi[w]; }
    }
    int sampled = (t < EPSV) ? sm.greedy : bi;
    float ls = lrow[sampled];
    float token_lp = (ls - m) - sm.L;
    sm.token_lp = token_lp;
    float* out_idx = out + B;
    float* out_lp = out + B + (size_t)B * (1 + nlp);
    size_t rb = (size_t)row * (1 + nlp);
    out[row] = (float)sampled;
    out_idx[rb] = (float)sampled;
    out_lp[rb] = token_lp;
    for (int j = 0; j < nlp; j++) {
      uint64_t cdv = sm.cand[j];
      out_idx[rb + 1 + j] = (float)(int)(uint32_t)(cdv & 0xffffffffu);
      out_lp[rb + 1 + j] = (fromOrd(~(uint32_t)(cdv >> 32)) - m) - sm.L;
    }
  }
  __syncthreads();
  const float Lc = sm.L, tlp = sm.token_lp;
  int cnt = 0;
  for (int i = tid; i < V4; i += FB_BLOCK) {
    float4 v = l4[i]; float a[4] = {v.x, v.y, v.z, v.w};
    #pragma unroll
    for (int c = 0; c < 4; c++) { float lp = (a[c] - m) - Lc; cnt += (lp >= tlp) ? 1 : 0; }
  }
  for (int i = Vt + tid; i < V; i += FB_BLOCK) {
    float lp = (lrow[i] - m) - Lc; cnt += (lp >= tlp) ? 1 : 0;
  }
  #pragma unroll
  for (int o = 32; o; o >>= 1) cnt += __shfl_down(cnt, o);
  if (lane == 0) sm.redi[wv] = cnt;
  __syncthreads();
  if (tid == 0) {
    int r = 0;
    for (int w = 0; w < FB_NW; w++) r += sm.redi[w];
    out[B + 2 * (size_t)B * (1 + nlp) + row] = (float)r;
  }
}

extern "C" void kernel_launch(void* const* d_in, const int* in_sizes, int n_in,
                              void* d_out, int out_size, void* d_ws, size_t ws_size,
                              hipStream_t stream) {
  const float* logits = (const float*)d_in[0];
  const float* temp   = (const float*)d_in[1];
  const float* minp   = (const float*)d_in[2];
  const float* topp   = (const float*)d_in[3];
  const int*   topk   = (const int*)d_in[4];
  const float* noise  = (const float*)d_in[5];
  int B = in_sizes[1];
  int V = in_sizes[0] / B;
  int nlp = (out_size / B - 4) / 2;
  if (nlp < 0) nlp = 0;

  uint8_t* ws = (uint8_t*)d_ws;
  size_t off = 0;
  uint32_t* pcnt = (uint32_t*)(ws + off); off += (size_t)B * NS * 4;
  float* pmax = (float*)(ws + off); off += (size_t)B * NS * 4;
  float* pS   = (float*)(ws + off); off += (size_t)B * NS * 4;
  off = (off + 7) & ~(size_t)7;
  uint64_t* cand = (uint64_t*)(ws + off); off += (size_t)B * NS * SEG * 8;

  if (ws_size < off) {
    hipLaunchKernelGGL(sampler_fallback, dim3(B), dim3(FB_BLOCK), 0, stream,
                       logits, temp, minp, topp, topk, noise, (float*)d_out, B, V, nlp);
    return;
  }

  hipLaunchKernelGGL(k3_fused, dim3(NS, B), dim3(K3B), 0, stream,
                     logits, pmax, pS, pcnt, cand, V);
  hipLaunchKernelGGL(k4_final, dim3(B), dim3(K4B), 0, stream,
                     temp, minp, topp, topk, noise, pmax, pS, pcnt, cand,
                     (float*)d_out, B, V, nlp);
}